// Round 2
// 425.526 us; speedup vs baseline: 1.0791x; 1.0791x over previous
//
#include <hip/hip_runtime.h>
#include <hip/hip_bf16.h>

#define BB 32
#define NN 512
#define MM 512
#define DD 1024

typedef __attribute__((ext_vector_type(8))) short short8;
typedef __attribute__((ext_vector_type(4))) float f32x4;

#define ASYNC_COPY16(g, l) \
    __builtin_amdgcn_global_load_lds((__attribute__((address_space(1))) void*)(g), \
                                     (__attribute__((address_space(3))) void*)(l), 16, 0, 0)

__device__ inline unsigned short f2bf(float f) {
    unsigned int u = __float_as_uint(f);
    u += 0x7fffu + ((u >> 16) & 1u);
    return (unsigned short)(u >> 16);
}

#define SPLIT1(vv, hh, ll) { unsigned short h_ = f2bf(vv); \
    float hf_ = __uint_as_float((unsigned int)h_ << 16); \
    hh = h_; ll = f2bf((vv) - hf_); }

// ---------------------------------------------------------------------------
// K0: fused split-convert + transpose. 256(r) x 64(c) tiles.
// ---------------------------------------------------------------------------
__device__ inline void conv_tile2(const float* __restrict__ src,
                                  unsigned short* __restrict__ h,
                                  unsigned short* __restrict__ l,
                                  unsigned short* __restrict__ hT,
                                  unsigned short* lds, int b, int r0, int c0, int t) {
    int i = t >> 4, j4 = (t & 15) * 4;
#pragma unroll
    for (int p = 0; p < 16; ++p) {
        int r = i + p * 16;
        size_t off = ((size_t)b * 512 + r0 + r) * 1024 + c0 + j4;
        float4 v = *(const float4*)&src[off];
        ushort4 hh, ll;
        SPLIT1(v.x, hh.x, ll.x) SPLIT1(v.y, hh.y, ll.y)
        SPLIT1(v.z, hh.z, ll.z) SPLIT1(v.w, hh.w, ll.w)
        *(ushort4*)&h[off] = hh;
        *(ushort4*)&l[off] = ll;
        *(ushort4*)&lds[r * 68 + j4] = hh;
    }
    __syncthreads();
    int c4 = t >> 6;            // 0..3
    int rr = (t & 63) * 4;      // 0..252
#pragma unroll
    for (int p = 0; p < 16; ++p) {
        int c = c4 + p * 4;     // 0..63
        ushort4 o;
        o.x = lds[(rr + 0) * 68 + c];
        o.y = lds[(rr + 1) * 68 + c];
        o.z = lds[(rr + 2) * 68 + c];
        o.w = lds[(rr + 3) * 68 + c];
        *(ushort4*)&hT[((size_t)b * 1024 + c0 + c) * 512 + r0 + rr] = o;
    }
}

__global__ __launch_bounds__(256) void convert_split_t(
    const float* __restrict__ x1, const float* __restrict__ x2,
    unsigned short* __restrict__ x1h, unsigned short* __restrict__ x1l,
    unsigned short* __restrict__ x1hT,
    unsigned short* __restrict__ x2h, unsigned short* __restrict__ x2l,
    unsigned short* __restrict__ x2hT) {
    int bid = blockIdx.x;
    int b = bid >> 5; int rem = bid & 31;
    int r0 = (rem >> 4) * 256, c0 = (rem & 15) * 64;
    __shared__ unsigned short lds[256 * 68];
    int t = threadIdx.x;
    conv_tile2(x1, x1h, x1l, x1hT, lds, b, r0, c0, t);
    __syncthreads();
    conv_tile2(x2, x2h, x2l, x2hT, lds, b, r0, c0, t);
}

// ---------------------------------------------------------------------------
// K1: align = x1 . x2^T (split-bf16, 3-term) + fused tile-local softmax
// partial stats. 128(n) x 128(m) tiles, 8 waves (512 thr), grid 512
// (2 blocks/CU, all co-resident). Double-buffered LDS prefetch (T3-min):
// stage tile k+1 while MFMAing tile k; one barrier per K-step.
// Each wave: 64n x 32m (4x2 frags of 16x16x32).
// ---------------------------------------------------------------------------
__global__ __launch_bounds__(512, 4) void gemm_align(
    const unsigned short* __restrict__ x1h, const unsigned short* __restrict__ x1l,
    const unsigned short* __restrict__ x2h, const unsigned short* __restrict__ x2l,
    const int* __restrict__ mask1, const int* __restrict__ mask2,
    float* __restrict__ alg,
    float* __restrict__ rp_max, float* __restrict__ rp_sum,
    float* __restrict__ cp_max, float* __restrict__ cp_sum) {
    // per buffer: Ah[128][32] | Al | Bh | Bl = 32KB; x2 buffers = 64KB
    __shared__ unsigned short S[2][16384];
    int bid = blockIdx.x;
    int nb = (bid & 7) * 64 + (bid >> 3);    // XCD batch-affinity swizzle (512 = 8*64)
    int b = nb >> 4; int tl = nb & 15;
    int nt = tl >> 2, mt = tl & 3;
    int n0 = nt * 128, m0 = mt * 128;
    int t = threadIdx.x; int w = t >> 6; int l = t & 63;
    int lane16 = l & 15, q = l >> 4, q8 = q * 8;
    int wr = (w >> 2) * 64;                  // wave row offset (0 or 64)
    int wc = (w & 3) * 32;                   // wave col offset (0/32/64/96)
    f32x4 acc[4][2];
#pragma unroll
    for (int i = 0; i < 4; ++i)
#pragma unroll
        for (int j = 0; j < 2; ++j) acc[i][j] = (f32x4){0.f, 0.f, 0.f, 0.f};
    // staging: 32 x 1KB wave-instructions per K-step, 4 per wave
    const unsigned short* gs[4];
    int ls[4];
#pragma unroll
    for (int s = 0; s < 4; ++s) {
        int qq = w * 4 + s;                  // 0..31
        int row0 = (qq & 7) * 16;
        const unsigned short* base; int lb;
        if (qq < 8)       { base = x1h + ((size_t)b * 512 + n0) * 1024; lb = 0; }
        else if (qq < 16) { base = x1l + ((size_t)b * 512 + n0) * 1024; lb = 4096; }
        else if (qq < 24) { base = x2h + ((size_t)b * 512 + m0) * 1024; lb = 8192; }
        else              { base = x2l + ((size_t)b * 512 + m0) * 1024; lb = 12288; }
        gs[s] = base + (size_t)(row0 + (l >> 2)) * 1024 + (l & 3) * 8;
        ls[s] = lb + row0 * 32 + l * 8;
    }
    // prologue: stage K-step 0 into buffer 0
#pragma unroll
    for (int s = 0; s < 4; ++s)
        ASYNC_COPY16(gs[s], &S[0][ls[s]]);
    __syncthreads();
    int cur = 0;
    for (int kk = 0; kk < 1024; kk += 32) {
        if (kk + 32 < 1024) {                // prefetch next K-step into other buffer
#pragma unroll
            for (int s = 0; s < 4; ++s)
                ASYNC_COPY16(gs[s] + kk + 32, &S[cur ^ 1][ls[s]]);
        }
        const unsigned short* Sb = S[cur];
        short8 ah[4], al[4], bh[2], bl[2];
#pragma unroll
        for (int i = 0; i < 4; ++i) {
            int off = (wr + i * 16 + lane16) * 32 + q8;
            ah[i] = *(const short8*)&Sb[off];
            al[i] = *(const short8*)&Sb[4096 + off];
        }
#pragma unroll
        for (int j = 0; j < 2; ++j) {
            int off = (wc + j * 16 + lane16) * 32 + q8;
            bh[j] = *(const short8*)&Sb[8192 + off];
            bl[j] = *(const short8*)&Sb[12288 + off];
        }
#pragma unroll
        for (int i = 0; i < 4; ++i)
#pragma unroll
            for (int j = 0; j < 2; ++j) {
                acc[i][j] = __builtin_amdgcn_mfma_f32_16x16x32_bf16(ah[i], bh[j], acc[i][j], 0, 0, 0);
                acc[i][j] = __builtin_amdgcn_mfma_f32_16x16x32_bf16(ah[i], bl[j], acc[i][j], 0, 0, 0);
                acc[i][j] = __builtin_amdgcn_mfma_f32_16x16x32_bf16(al[i], bh[j], acc[i][j], 0, 0, 0);
            }
        __syncthreads();    // drains vmcnt (prefetch landed) + protects buffer reuse
        cur ^= 1;
    }
    // ---- C store ----
    float* ob = alg + ((size_t)b * 512 + n0 + wr) * 512 + m0 + wc;
    int q4 = q * 4;
#pragma unroll
    for (int i = 0; i < 4; ++i)
#pragma unroll
        for (int j = 0; j < 2; ++j)
#pragma unroll
            for (int r = 0; r < 4; ++r)
                ob[(size_t)(i * 16 + q4 + r) * 512 + j * 16 + lane16] = acc[i][j][r];
    // ---- masks ----
    int mk2[2];
#pragma unroll
    for (int j = 0; j < 2; ++j) mk2[j] = mask2[b * 512 + m0 + wc + j * 16 + lane16];
    int mk1r[4][4];
#pragma unroll
    for (int i = 0; i < 4; ++i)
#pragma unroll
        for (int r = 0; r < 4; ++r) mk1r[i][r] = mask1[b * 512 + n0 + wr + i * 16 + q4 + r];
    // ---- col partials (this wave's 64 n-rows, per m-col); 64-row groups keep
    //      cp granularity at 8 per batch, so combine_stats is unchanged ----
#pragma unroll
    for (int j = 0; j < 2; ++j) {
        float cm = -3.0e38f;
#pragma unroll
        for (int i = 0; i < 4; ++i)
#pragma unroll
            for (int r = 0; r < 4; ++r)
                if (mk1r[i][r]) cm = fmaxf(cm, acc[i][j][r]);
        cm = fmaxf(cm, __shfl_xor(cm, 16));
        cm = fmaxf(cm, __shfl_xor(cm, 32));
        float cs = 0.f;
#pragma unroll
        for (int i = 0; i < 4; ++i)
#pragma unroll
            for (int r = 0; r < 4; ++r)
                cs += mk1r[i][r] ? __expf(acc[i][j][r] - cm) : 0.f;
        cs += __shfl_xor(cs, 16);
        cs += __shfl_xor(cs, 32);
        if (q == 0) {
            size_t o = ((size_t)b * 8 + nt * 2 + (w >> 2)) * 512 + m0 + wc + j * 16 + lane16;
            cp_max[o] = cm;
            cp_sum[o] = cs;
        }
    }
    // ---- row partials (this wave's 32 m-cols per n-row); combine the 4 waves
    //      sharing a wave-row in LDS. rp granularity 4 per batch (unchanged). ----
    float* rmS = (float*)&S[0][0];     // [8][64]
    float* rsS = rmS + 512;            // [8][64]
#pragma unroll
    for (int i = 0; i < 4; ++i)
#pragma unroll
        for (int r = 0; r < 4; ++r) {
            float v0 = acc[i][0][r], v1 = acc[i][1][r];
            float rm = fmaxf(mk2[0] ? v0 : -3.0e38f, mk2[1] ? v1 : -3.0e38f);
            rm = fmaxf(rm, __shfl_xor(rm, 1));
            rm = fmaxf(rm, __shfl_xor(rm, 2));
            rm = fmaxf(rm, __shfl_xor(rm, 4));
            rm = fmaxf(rm, __shfl_xor(rm, 8));
            float rs = (mk2[0] ? __expf(v0 - rm) : 0.f) + (mk2[1] ? __expf(v1 - rm) : 0.f);
            rs += __shfl_xor(rs, 1);
            rs += __shfl_xor(rs, 2);
            rs += __shfl_xor(rs, 4);
            rs += __shfl_xor(rs, 8);
            if (lane16 == 0) {
                int row = i * 16 + q4 + r;
                rmS[w * 64 + row] = rm;
                rsS[w * 64 + row] = rs;
            }
        }
    __syncthreads();
    if (t < 128) {
        int grp = t >> 6, rloc = t & 63;
        float M = -3.0e38f;
#pragma unroll
        for (int ww = 0; ww < 4; ++ww) M = fmaxf(M, rmS[(grp * 4 + ww) * 64 + rloc]);
        float Ssum = 0.f;
#pragma unroll
        for (int ww = 0; ww < 4; ++ww)
            Ssum += rsS[(grp * 4 + ww) * 64 + rloc] * __expf(rmS[(grp * 4 + ww) * 64 + rloc] - M);
        size_t o = ((size_t)b * 4 + mt) * 512 + n0 + t;
        rp_max[o] = M;
        rp_sum[o] = Ssum;
    }
}

// ---------------------------------------------------------------------------
// K2: combine partials -> rowmax/rowinv (per b,n) and colmax/colinv (per b,m)
// ---------------------------------------------------------------------------
__global__ __launch_bounds__(256) void combine_stats(
    const float* __restrict__ rp_max, const float* __restrict__ rp_sum,
    const float* __restrict__ cp_max, const float* __restrict__ cp_sum,
    float* __restrict__ rowmax, float* __restrict__ rowinv,
    float* __restrict__ colmax, float* __restrict__ colinv) {
    int idx = blockIdx.x * 256 + threadIdx.x;   // 0..32767
    if (idx < 16384) {
        int b = idx >> 9, n = idx & 511;
        float M = -3.0e38f;
#pragma unroll
        for (int tt = 0; tt < 4; ++tt) M = fmaxf(M, rp_max[((size_t)b * 4 + tt) * 512 + n]);
        float S = 0.f;
#pragma unroll
        for (int tt = 0; tt < 4; ++tt) {
            size_t o = ((size_t)b * 4 + tt) * 512 + n;
            S += rp_sum[o] * __expf(rp_max[o] - M);
        }
        rowmax[idx] = M;
        rowinv[idx] = 1.0f / S;
    } else {
        int id2 = idx - 16384;
        int b = id2 >> 9, m = id2 & 511;
        float M = -3.0e38f;
#pragma unroll
        for (int tt = 0; tt < 8; ++tt) M = fmaxf(M, cp_max[((size_t)b * 8 + tt) * 512 + m]);
        float S = 0.f;
#pragma unroll
        for (int tt = 0; tt < 8; ++tt) {
            size_t o = ((size_t)b * 8 + tt) * 512 + m;
            S += cp_sum[o] * __expf(cp_max[o] - M);
        }
        colmax[id2] = M;
        colinv[id2] = 1.0f / S;
    }
}

// ---------------------------------------------------------------------------
// K3: apply — read align once, write attn12[n][m] and attn21[m][n] (bf16)
// ---------------------------------------------------------------------------
__global__ __launch_bounds__(256) void apply_softmax(
    const float* __restrict__ alg, const int* __restrict__ mask1,
    const int* __restrict__ mask2,
    const float* __restrict__ rowmax, const float* __restrict__ rowinv,
    const float* __restrict__ colmax, const float* __restrict__ colinv,
    unsigned short* __restrict__ attn12, unsigned short* __restrict__ attn21) {
    int bid = blockIdx.x; int b = bid >> 6; int rem = bid & 63;
    int m0 = (rem >> 3) * 64, n0 = (rem & 7) * 64;
    int t = threadIdx.x;
    __shared__ float lds[64 * 65];
    int jj = t & 63; int ii = t >> 6;
    int mk2 = mask2[b * 512 + m0 + jj];
#pragma unroll
    for (int p = 0; p < 16; ++p) {
        int n = ii + p * 4;
        float v = alg[((size_t)b * 512 + n0 + n) * 512 + m0 + jj];
        lds[n * 65 + jj] = v;
        float rm = rowmax[b * 512 + n0 + n];
        float ri = rowinv[b * 512 + n0 + n];
        float e = mk2 ? __expf(v - rm) * ri : 0.f;
        attn12[((size_t)b * 512 + n0 + n) * 512 + m0 + jj] = f2bf(e);
    }
    __syncthreads();
    int mk1 = mask1[b * 512 + n0 + jj];
#pragma unroll
    for (int p = 0; p < 16; ++p) {
        int mm = ii + p * 4;
        float cm = colmax[b * 512 + m0 + mm];
        float ci = colinv[b * 512 + m0 + mm];
        float v = lds[jj * 65 + mm];
        unsigned short pv = mk1 ? f2bf(__expf(v - cm) * ci) : (unsigned short)0;
        attn21[((size_t)b * 512 + m0 + mm) * 512 + n0 + jj] = pv;
    }
}

// ---------------------------------------------------------------------------
// K4/K5: out[b][r][d] = sum_k P[b][r][k] * VT[b][d][k]  (bf16 MFMA, async,
// double-buffered prefetch: stage k+1 while MFMAing k; 1 barrier/K-step)
// ---------------------------------------------------------------------------
__global__ __launch_bounds__(256) void gemm_pv(
    const unsigned short* __restrict__ P, const unsigned short* __restrict__ VT,
    float* __restrict__ out) {
    __shared__ unsigned short S[2][2][4096];   // [dbuf][A/B][128*32] = 32KB
    int bid = blockIdx.x;
    int nb = (bid & 7) * 128 + (bid >> 3);  // XCD batch-affinity swizzle
    int b = nb >> 5; int rem = nb & 31;
    int n0 = (rem >> 3) * 128, d0 = (rem & 7) * 128;
    int t = threadIdx.x; int w = t >> 6; int l = t & 63;
    int lane16 = l & 15, q8 = (l >> 4) * 8;
    int wr = (w >> 1) * 64, wc = (w & 1) * 64;
    f32x4 acc[4][4];
#pragma unroll
    for (int i = 0; i < 4; ++i)
#pragma unroll
        for (int j = 0; j < 4; ++j) acc[i][j] = (f32x4){0.f, 0.f, 0.f, 0.f};
    const unsigned short* gA = P + ((size_t)b * 512 + n0) * 512;
    const unsigned short* gB = VT + ((size_t)b * DD + d0) * 512;
    int w2 = w & 1;
    int side = (w < 2) ? 0 : 1;
    const unsigned short* gp = (w < 2) ? gA : gB;
    const unsigned short* gbase = gp + (size_t)(w2 * 64 + (l >> 2)) * 512 + (l & 3) * 8;
    int lofs = w2 * 2048;
    // prologue: stage K-step 0 into buffer 0
#pragma unroll
    for (int p = 0; p < 4; ++p)
        ASYNC_COPY16(gbase + (size_t)(p * 16) * 512, &S[0][side][lofs + p * 512]);
    __syncthreads();
    int cur = 0;
    for (int kk = 0; kk < 512; kk += 32) {
        if (kk + 32 < 512) {
#pragma unroll
            for (int p = 0; p < 4; ++p)
                ASYNC_COPY16(gbase + (size_t)(p * 16) * 512 + kk + 32,
                             &S[cur ^ 1][side][lofs + p * 512]);
        }
        short8 af[4], bf[4];
#pragma unroll
        for (int i = 0; i < 4; ++i)
            af[i] = *(const short8*)&S[cur][0][(wr + i * 16 + lane16) * 32 + q8];
#pragma unroll
        for (int j = 0; j < 4; ++j)
            bf[j] = *(const short8*)&S[cur][1][(wc + j * 16 + lane16) * 32 + q8];
#pragma unroll
        for (int i = 0; i < 4; ++i)
#pragma unroll
            for (int j = 0; j < 4; ++j)
                acc[i][j] = __builtin_amdgcn_mfma_f32_16x16x32_bf16(af[i], bf[j], acc[i][j], 0, 0, 0);
        __syncthreads();
        cur ^= 1;
    }
    int q4 = (l >> 4) * 4;
#pragma unroll
    for (int i = 0; i < 4; ++i)
#pragma unroll
        for (int j = 0; j < 4; ++j)
#pragma unroll
            for (int r = 0; r < 4; ++r) {
                int rr = n0 + wr + i * 16 + q4 + r;
                int dd = d0 + wc + j * 16 + lane16;
                out[((size_t)b * 512 + rr) * DD + dd] = acc[i][j][r];
            }
}

// ---------------------------------------------------------------------------
// ws layout (224MB): x1h 0 | x2h 32M | x1hT 64M | x2hT 96M | x1l 128M |
//   x2l 160M | alg 192M.  After gemm_align: attn12 @128M (16MB), stats
//   @144M (256KB), attn21 @160M (16MB).  Partials live in d_out scratch
//   (overwritten by gemm_pv afterwards).
// ---------------------------------------------------------------------------
extern "C" void kernel_launch(void* const* d_in, const int* in_sizes, int n_in,
                              void* d_out, int out_size, void* d_ws, size_t ws_size,
                              hipStream_t stream) {
    const float* x1 = (const float*)d_in[0];
    const float* x2 = (const float*)d_in[1];
    const int* mask1 = (const int*)d_in[2];
    const int* mask2 = (const int*)d_in[3];
    char* ws = (char*)d_ws;
    unsigned short* x1h  = (unsigned short*)(ws);
    unsigned short* x2h  = (unsigned short*)(ws + 33554432UL);
    unsigned short* x1hT = (unsigned short*)(ws + 67108864UL);
    unsigned short* x2hT = (unsigned short*)(ws + 100663296UL);
    unsigned short* x1l  = (unsigned short*)(ws + 134217728UL);
    unsigned short* x2l  = (unsigned short*)(ws + 167772160UL);
    float* alg           = (float*)(ws + 201326592UL);
    unsigned short* attn12 = (unsigned short*)(ws + 134217728UL);  // reuses x1l
    float* rowmax        = (float*)(ws + 150994944UL);             // @144MB
    float* rowinv        = (float*)(ws + 151060480UL);
    float* colmax        = (float*)(ws + 151126016UL);
    float* colinv        = (float*)(ws + 151191552UL);
    unsigned short* attn21 = (unsigned short*)(ws + 167772160UL);  // reuses x2l
    float* out1 = (float*)d_out;
    float* out2 = out1 + (size_t)BB * NN * DD;
    // partial stats scratch in d_out (dead before gemm_pv writes it)
    float* rp_max = (float*)d_out;            // [32][4][512]
    float* rp_sum = rp_max + 65536;
    float* cp_max = rp_sum + 65536;           // [32][8][512]
    float* cp_sum = cp_max + 131072;

    convert_split_t<<<1024, 256, 0, stream>>>(x1, x2, x1h, x1l, x1hT, x2h, x2l, x2hT);
    gemm_align<<<512, 512, 0, stream>>>(x1h, x1l, x2h, x2l, mask1, mask2, alg,
                                        rp_max, rp_sum, cp_max, cp_sum);
    combine_stats<<<128, 256, 0, stream>>>(rp_max, rp_sum, cp_max, cp_sum,
                                           rowmax, rowinv, colmax, colinv);
    apply_softmax<<<2048, 256, 0, stream>>>(alg, mask1, mask2, rowmax, rowinv,
                                            colmax, colinv, attn12, attn21);
    gemm_pv<<<1024, 256, 0, stream>>>(attn12, x2hT, out1);
    gemm_pv<<<1024, 256, 0, stream>>>(attn21, x1hT, out2);
}

// Round 3
// 425.227 us; speedup vs baseline: 1.0798x; 1.0007x over previous
//
#include <hip/hip_runtime.h>
#include <hip/hip_bf16.h>

#define BB 32
#define NN 512
#define MM 512
#define DD 1024

typedef __attribute__((ext_vector_type(8))) short short8;
typedef __attribute__((ext_vector_type(4))) float f32x4;

#define ASYNC_COPY16(g, l) \
    __builtin_amdgcn_global_load_lds((__attribute__((address_space(1))) void*)(g), \
                                     (__attribute__((address_space(3))) void*)(l), 16, 0, 0)

__device__ inline unsigned short f2bf(float f) {
    unsigned int u = __float_as_uint(f);
    u += 0x7fffu + ((u >> 16) & 1u);
    return (unsigned short)(u >> 16);
}

#define SPLIT1(vv, hh, ll) { unsigned short h_ = f2bf(vv); \
    float hf_ = __uint_as_float((unsigned int)h_ << 16); \
    hh = h_; ll = f2bf((vv) - hf_); }

// ---------------------------------------------------------------------------
// K0: fused split-convert + transpose. 128(r) x 64(c) tiles, one source per
// block (grid 4096 = 2 src x 32 b x 4 rt x 16 ct). LDS tile is COLUMN-major
// (T[c][r], stride 130 elems -> word-stride 65 === 1 mod 32): phase-1 u16
// scatter-writes ~4-way (1.58x), phase-2 b32 reads ~2-way (free), hT store
// is an 8B coalesced uint2. 16.6KB LDS -> 8 blocks/CU (32 waves, full occ).
// ---------------------------------------------------------------------------
__global__ __launch_bounds__(256) void convert_split_t(
    const float* __restrict__ x1, const float* __restrict__ x2,
    unsigned short* __restrict__ x1h, unsigned short* __restrict__ x1l,
    unsigned short* __restrict__ x1hT,
    unsigned short* __restrict__ x2h, unsigned short* __restrict__ x2l,
    unsigned short* __restrict__ x2hT) {
    int bid = blockIdx.x;
    const float* src; unsigned short *h, *l, *hT;
    if (bid < 2048) { src = x1; h = x1h; l = x1l; hT = x1hT; }
    else            { src = x2; h = x2h; l = x2l; hT = x2hT; bid -= 2048; }
    int b = bid >> 6; int rem = bid & 63;
    int r0 = (rem >> 4) * 128, c0 = (rem & 15) * 64;
    __shared__ unsigned short T[64 * 130];   // T[c][r], stride 130
    int t = threadIdx.x;
    int i = t >> 4, j4 = (t & 15) * 4;
#pragma unroll
    for (int p = 0; p < 8; ++p) {
        int r = i + p * 16;
        size_t off = ((size_t)b * 512 + r0 + r) * 1024 + c0 + j4;
        float4 v = *(const float4*)&src[off];
        ushort4 hh, ll;
        SPLIT1(v.x, hh.x, ll.x) SPLIT1(v.y, hh.y, ll.y)
        SPLIT1(v.z, hh.z, ll.z) SPLIT1(v.w, hh.w, ll.w)
        *(ushort4*)&h[off] = hh;
        *(ushort4*)&l[off] = ll;
        T[(j4 + 0) * 130 + r] = hh.x;
        T[(j4 + 1) * 130 + r] = hh.y;
        T[(j4 + 2) * 130 + r] = hh.z;
        T[(j4 + 3) * 130 + r] = hh.w;
    }
    __syncthreads();
    int rr = (t & 31) * 4;      // 0..124
    int cb = t >> 5;            // 0..7
#pragma unroll
    for (int pp = 0; pp < 8; ++pp) {
        int c = cb + pp * 8;    // 0..63
        uint2 o;
        o.x = *(const unsigned int*)&T[c * 130 + rr];
        o.y = *(const unsigned int*)&T[c * 130 + rr + 2];
        *(uint2*)&hT[((size_t)b * 1024 + c0 + c) * 512 + r0 + rr] = o;
    }
}

// ---------------------------------------------------------------------------
// K1: align = x1 . x2^T (split-bf16, 3-term) + fused tile-local softmax
// partial stats. 128(n) x 128(m) tiles, 8 waves (512 thr), grid 512
// (2 blocks/CU, all co-resident). Double-buffered LDS prefetch (T3-min):
// stage tile k+1 while MFMAing tile k; one barrier per K-step.
// Each wave: 64n x 32m (4x2 frags of 16x16x32).
// ---------------------------------------------------------------------------
__global__ __launch_bounds__(512, 4) void gemm_align(
    const unsigned short* __restrict__ x1h, const unsigned short* __restrict__ x1l,
    const unsigned short* __restrict__ x2h, const unsigned short* __restrict__ x2l,
    const int* __restrict__ mask1, const int* __restrict__ mask2,
    float* __restrict__ alg,
    float* __restrict__ rp_max, float* __restrict__ rp_sum,
    float* __restrict__ cp_max, float* __restrict__ cp_sum) {
    // per buffer: Ah[128][32] | Al | Bh | Bl = 32KB; x2 buffers = 64KB
    __shared__ unsigned short S[2][16384];
    int bid = blockIdx.x;
    int nb = (bid & 7) * 64 + (bid >> 3);    // XCD batch-affinity swizzle (512 = 8*64)
    int b = nb >> 4; int tl = nb & 15;
    int nt = tl >> 2, mt = tl & 3;
    int n0 = nt * 128, m0 = mt * 128;
    int t = threadIdx.x; int w = t >> 6; int l = t & 63;
    int lane16 = l & 15, q = l >> 4, q8 = q * 8;
    int wr = (w >> 2) * 64;                  // wave row offset (0 or 64)
    int wc = (w & 3) * 32;                   // wave col offset (0/32/64/96)
    f32x4 acc[4][2];
#pragma unroll
    for (int i = 0; i < 4; ++i)
#pragma unroll
        for (int j = 0; j < 2; ++j) acc[i][j] = (f32x4){0.f, 0.f, 0.f, 0.f};
    // staging: 32 x 1KB wave-instructions per K-step, 4 per wave
    const unsigned short* gs[4];
    int ls[4];
#pragma unroll
    for (int s = 0; s < 4; ++s) {
        int qq = w * 4 + s;                  // 0..31
        int row0 = (qq & 7) * 16;
        const unsigned short* base; int lb;
        if (qq < 8)       { base = x1h + ((size_t)b * 512 + n0) * 1024; lb = 0; }
        else if (qq < 16) { base = x1l + ((size_t)b * 512 + n0) * 1024; lb = 4096; }
        else if (qq < 24) { base = x2h + ((size_t)b * 512 + m0) * 1024; lb = 8192; }
        else              { base = x2l + ((size_t)b * 512 + m0) * 1024; lb = 12288; }
        gs[s] = base + (size_t)(row0 + (l >> 2)) * 1024 + (l & 3) * 8;
        ls[s] = lb + row0 * 32 + l * 8;
    }
    // prologue: stage K-step 0 into buffer 0
#pragma unroll
    for (int s = 0; s < 4; ++s)
        ASYNC_COPY16(gs[s], &S[0][ls[s]]);
    __syncthreads();
    int cur = 0;
    for (int kk = 0; kk < 1024; kk += 32) {
        if (kk + 32 < 1024) {                // prefetch next K-step into other buffer
#pragma unroll
            for (int s = 0; s < 4; ++s)
                ASYNC_COPY16(gs[s] + kk + 32, &S[cur ^ 1][ls[s]]);
        }
        const unsigned short* Sb = S[cur];
        short8 ah[4], al[4], bh[2], bl[2];
#pragma unroll
        for (int i = 0; i < 4; ++i) {
            int off = (wr + i * 16 + lane16) * 32 + q8;
            ah[i] = *(const short8*)&Sb[off];
            al[i] = *(const short8*)&Sb[4096 + off];
        }
#pragma unroll
        for (int j = 0; j < 2; ++j) {
            int off = (wc + j * 16 + lane16) * 32 + q8;
            bh[j] = *(const short8*)&Sb[8192 + off];
            bl[j] = *(const short8*)&Sb[12288 + off];
        }
#pragma unroll
        for (int i = 0; i < 4; ++i)
#pragma unroll
            for (int j = 0; j < 2; ++j) {
                acc[i][j] = __builtin_amdgcn_mfma_f32_16x16x32_bf16(ah[i], bh[j], acc[i][j], 0, 0, 0);
                acc[i][j] = __builtin_amdgcn_mfma_f32_16x16x32_bf16(ah[i], bl[j], acc[i][j], 0, 0, 0);
                acc[i][j] = __builtin_amdgcn_mfma_f32_16x16x32_bf16(al[i], bh[j], acc[i][j], 0, 0, 0);
            }
        __syncthreads();    // drains vmcnt (prefetch landed) + protects buffer reuse
        cur ^= 1;
    }
    // ---- C store ----
    float* ob = alg + ((size_t)b * 512 + n0 + wr) * 512 + m0 + wc;
    int q4 = q * 4;
#pragma unroll
    for (int i = 0; i < 4; ++i)
#pragma unroll
        for (int j = 0; j < 2; ++j)
#pragma unroll
            for (int r = 0; r < 4; ++r)
                ob[(size_t)(i * 16 + q4 + r) * 512 + j * 16 + lane16] = acc[i][j][r];
    // ---- masks ----
    int mk2[2];
#pragma unroll
    for (int j = 0; j < 2; ++j) mk2[j] = mask2[b * 512 + m0 + wc + j * 16 + lane16];
    int mk1r[4][4];
#pragma unroll
    for (int i = 0; i < 4; ++i)
#pragma unroll
        for (int r = 0; r < 4; ++r) mk1r[i][r] = mask1[b * 512 + n0 + wr + i * 16 + q4 + r];
    // ---- col partials (this wave's 64 n-rows, per m-col); 64-row groups keep
    //      cp granularity at 8 per batch, so combine_stats is unchanged ----
#pragma unroll
    for (int j = 0; j < 2; ++j) {
        float cm = -3.0e38f;
#pragma unroll
        for (int i = 0; i < 4; ++i)
#pragma unroll
            for (int r = 0; r < 4; ++r)
                if (mk1r[i][r]) cm = fmaxf(cm, acc[i][j][r]);
        cm = fmaxf(cm, __shfl_xor(cm, 16));
        cm = fmaxf(cm, __shfl_xor(cm, 32));
        float cs = 0.f;
#pragma unroll
        for (int i = 0; i < 4; ++i)
#pragma unroll
            for (int r = 0; r < 4; ++r)
                cs += mk1r[i][r] ? __expf(acc[i][j][r] - cm) : 0.f;
        cs += __shfl_xor(cs, 16);
        cs += __shfl_xor(cs, 32);
        if (q == 0) {
            size_t o = ((size_t)b * 8 + nt * 2 + (w >> 2)) * 512 + m0 + wc + j * 16 + lane16;
            cp_max[o] = cm;
            cp_sum[o] = cs;
        }
    }
    // ---- row partials (this wave's 32 m-cols per n-row); combine the 4 waves
    //      sharing a wave-row in LDS. rp granularity 4 per batch (unchanged). ----
    float* rmS = (float*)&S[0][0];     // [8][64]
    float* rsS = rmS + 512;            // [8][64]
#pragma unroll
    for (int i = 0; i < 4; ++i)
#pragma unroll
        for (int r = 0; r < 4; ++r) {
            float v0 = acc[i][0][r], v1 = acc[i][1][r];
            float rm = fmaxf(mk2[0] ? v0 : -3.0e38f, mk2[1] ? v1 : -3.0e38f);
            rm = fmaxf(rm, __shfl_xor(rm, 1));
            rm = fmaxf(rm, __shfl_xor(rm, 2));
            rm = fmaxf(rm, __shfl_xor(rm, 4));
            rm = fmaxf(rm, __shfl_xor(rm, 8));
            float rs = (mk2[0] ? __expf(v0 - rm) : 0.f) + (mk2[1] ? __expf(v1 - rm) : 0.f);
            rs += __shfl_xor(rs, 1);
            rs += __shfl_xor(rs, 2);
            rs += __shfl_xor(rs, 4);
            rs += __shfl_xor(rs, 8);
            if (lane16 == 0) {
                int row = i * 16 + q4 + r;
                rmS[w * 64 + row] = rm;
                rsS[w * 64 + row] = rs;
            }
        }
    __syncthreads();
    if (t < 128) {
        int grp = t >> 6, rloc = t & 63;
        float M = -3.0e38f;
#pragma unroll
        for (int ww = 0; ww < 4; ++ww) M = fmaxf(M, rmS[(grp * 4 + ww) * 64 + rloc]);
        float Ssum = 0.f;
#pragma unroll
        for (int ww = 0; ww < 4; ++ww)
            Ssum += rsS[(grp * 4 + ww) * 64 + rloc] * __expf(rmS[(grp * 4 + ww) * 64 + rloc] - M);
        size_t o = ((size_t)b * 4 + mt) * 512 + n0 + t;
        rp_max[o] = M;
        rp_sum[o] = Ssum;
    }
}

// ---------------------------------------------------------------------------
// K2: combine partials -> rowmax/rowinv (per b,n) and colmax/colinv (per b,m)
// ---------------------------------------------------------------------------
__global__ __launch_bounds__(256) void combine_stats(
    const float* __restrict__ rp_max, const float* __restrict__ rp_sum,
    const float* __restrict__ cp_max, const float* __restrict__ cp_sum,
    float* __restrict__ rowmax, float* __restrict__ rowinv,
    float* __restrict__ colmax, float* __restrict__ colinv) {
    int idx = blockIdx.x * 256 + threadIdx.x;   // 0..32767
    if (idx < 16384) {
        int b = idx >> 9, n = idx & 511;
        float M = -3.0e38f;
#pragma unroll
        for (int tt = 0; tt < 4; ++tt) M = fmaxf(M, rp_max[((size_t)b * 4 + tt) * 512 + n]);
        float S = 0.f;
#pragma unroll
        for (int tt = 0; tt < 4; ++tt) {
            size_t o = ((size_t)b * 4 + tt) * 512 + n;
            S += rp_sum[o] * __expf(rp_max[o] - M);
        }
        rowmax[idx] = M;
        rowinv[idx] = 1.0f / S;
    } else {
        int id2 = idx - 16384;
        int b = id2 >> 9, m = id2 & 511;
        float M = -3.0e38f;
#pragma unroll
        for (int tt = 0; tt < 8; ++tt) M = fmaxf(M, cp_max[((size_t)b * 8 + tt) * 512 + m]);
        float S = 0.f;
#pragma unroll
        for (int tt = 0; tt < 8; ++tt) {
            size_t o = ((size_t)b * 8 + tt) * 512 + m;
            S += cp_sum[o] * __expf(cp_max[o] - M);
        }
        colmax[id2] = M;
        colinv[id2] = 1.0f / S;
    }
}

// ---------------------------------------------------------------------------
// K3: apply — read align once, write attn12[n][m] and attn21[m][n] (bf16)
// ---------------------------------------------------------------------------
__global__ __launch_bounds__(256) void apply_softmax(
    const float* __restrict__ alg, const int* __restrict__ mask1,
    const int* __restrict__ mask2,
    const float* __restrict__ rowmax, const float* __restrict__ rowinv,
    const float* __restrict__ colmax, const float* __restrict__ colinv,
    unsigned short* __restrict__ attn12, unsigned short* __restrict__ attn21) {
    int bid = blockIdx.x; int b = bid >> 6; int rem = bid & 63;
    int m0 = (rem >> 3) * 64, n0 = (rem & 7) * 64;
    int t = threadIdx.x;
    __shared__ float lds[64 * 65];
    int jj = t & 63; int ii = t >> 6;
    int mk2 = mask2[b * 512 + m0 + jj];
#pragma unroll
    for (int p = 0; p < 16; ++p) {
        int n = ii + p * 4;
        float v = alg[((size_t)b * 512 + n0 + n) * 512 + m0 + jj];
        lds[n * 65 + jj] = v;
        float rm = rowmax[b * 512 + n0 + n];
        float ri = rowinv[b * 512 + n0 + n];
        float e = mk2 ? __expf(v - rm) * ri : 0.f;
        attn12[((size_t)b * 512 + n0 + n) * 512 + m0 + jj] = f2bf(e);
    }
    __syncthreads();
    int mk1 = mask1[b * 512 + n0 + jj];
#pragma unroll
    for (int p = 0; p < 16; ++p) {
        int mm = ii + p * 4;
        float cm = colmax[b * 512 + m0 + mm];
        float ci = colinv[b * 512 + m0 + mm];
        float v = lds[jj * 65 + mm];
        unsigned short pv = mk1 ? f2bf(__expf(v - cm) * ci) : (unsigned short)0;
        attn21[((size_t)b * 512 + m0 + mm) * 512 + n0 + jj] = pv;
    }
}

// ---------------------------------------------------------------------------
// K4/K5: out[b][r][d] = sum_k P[b][r][k] * VT[b][d][k]  (bf16 MFMA, async,
// double-buffered prefetch: stage k+1 while MFMAing k; 1 barrier/K-step)
// ---------------------------------------------------------------------------
__global__ __launch_bounds__(256) void gemm_pv(
    const unsigned short* __restrict__ P, const unsigned short* __restrict__ VT,
    float* __restrict__ out) {
    __shared__ unsigned short S[2][2][4096];   // [dbuf][A/B][128*32] = 32KB
    int bid = blockIdx.x;
    int nb = (bid & 7) * 128 + (bid >> 3);  // XCD batch-affinity swizzle
    int b = nb >> 5; int rem = nb & 31;
    int n0 = (rem >> 3) * 128, d0 = (rem & 7) * 128;
    int t = threadIdx.x; int w = t >> 6; int l = t & 63;
    int lane16 = l & 15, q8 = (l >> 4) * 8;
    int wr = (w >> 1) * 64, wc = (w & 1) * 64;
    f32x4 acc[4][4];
#pragma unroll
    for (int i = 0; i < 4; ++i)
#pragma unroll
        for (int j = 0; j < 4; ++j) acc[i][j] = (f32x4){0.f, 0.f, 0.f, 0.f};
    const unsigned short* gA = P + ((size_t)b * 512 + n0) * 512;
    const unsigned short* gB = VT + ((size_t)b * DD + d0) * 512;
    int w2 = w & 1;
    int side = (w < 2) ? 0 : 1;
    const unsigned short* gp = (w < 2) ? gA : gB;
    const unsigned short* gbase = gp + (size_t)(w2 * 64 + (l >> 2)) * 512 + (l & 3) * 8;
    int lofs = w2 * 2048;
    // prologue: stage K-step 0 into buffer 0
#pragma unroll
    for (int p = 0; p < 4; ++p)
        ASYNC_COPY16(gbase + (size_t)(p * 16) * 512, &S[0][side][lofs + p * 512]);
    __syncthreads();
    int cur = 0;
    for (int kk = 0; kk < 512; kk += 32) {
        if (kk + 32 < 512) {
#pragma unroll
            for (int p = 0; p < 4; ++p)
                ASYNC_COPY16(gbase + (size_t)(p * 16) * 512 + kk + 32,
                             &S[cur ^ 1][side][lofs + p * 512]);
        }
        short8 af[4], bf[4];
#pragma unroll
        for (int i = 0; i < 4; ++i)
            af[i] = *(const short8*)&S[cur][0][(wr + i * 16 + lane16) * 32 + q8];
#pragma unroll
        for (int j = 0; j < 4; ++j)
            bf[j] = *(const short8*)&S[cur][1][(wc + j * 16 + lane16) * 32 + q8];
#pragma unroll
        for (int i = 0; i < 4; ++i)
#pragma unroll
            for (int j = 0; j < 4; ++j)
                acc[i][j] = __builtin_amdgcn_mfma_f32_16x16x32_bf16(af[i], bf[j], acc[i][j], 0, 0, 0);
        __syncthreads();
        cur ^= 1;
    }
    int q4 = (l >> 4) * 4;
#pragma unroll
    for (int i = 0; i < 4; ++i)
#pragma unroll
        for (int j = 0; j < 4; ++j)
#pragma unroll
            for (int r = 0; r < 4; ++r) {
                int rr = n0 + wr + i * 16 + q4 + r;
                int dd = d0 + wc + j * 16 + lane16;
                out[((size_t)b * 512 + rr) * DD + dd] = acc[i][j][r];
            }
}

// ---------------------------------------------------------------------------
// ws layout (224MB): x1h 0 | x2h 32M | x1hT 64M | x2hT 96M | x1l 128M |
//   x2l 160M | alg 192M.  After gemm_align: attn12 @128M (16MB), stats
//   @144M (256KB), attn21 @160M (16MB).  Partials live in d_out scratch
//   (overwritten by gemm_pv afterwards).
// ---------------------------------------------------------------------------
extern "C" void kernel_launch(void* const* d_in, const int* in_sizes, int n_in,
                              void* d_out, int out_size, void* d_ws, size_t ws_size,
                              hipStream_t stream) {
    const float* x1 = (const float*)d_in[0];
    const float* x2 = (const float*)d_in[1];
    const int* mask1 = (const int*)d_in[2];
    const int* mask2 = (const int*)d_in[3];
    char* ws = (char*)d_ws;
    unsigned short* x1h  = (unsigned short*)(ws);
    unsigned short* x2h  = (unsigned short*)(ws + 33554432UL);
    unsigned short* x1hT = (unsigned short*)(ws + 67108864UL);
    unsigned short* x2hT = (unsigned short*)(ws + 100663296UL);
    unsigned short* x1l  = (unsigned short*)(ws + 134217728UL);
    unsigned short* x2l  = (unsigned short*)(ws + 167772160UL);
    float* alg           = (float*)(ws + 201326592UL);
    unsigned short* attn12 = (unsigned short*)(ws + 134217728UL);  // reuses x1l
    float* rowmax        = (float*)(ws + 150994944UL);             // @144MB
    float* rowinv        = (float*)(ws + 151060480UL);
    float* colmax        = (float*)(ws + 151126016UL);
    float* colinv        = (float*)(ws + 151191552UL);
    unsigned short* attn21 = (unsigned short*)(ws + 167772160UL);  // reuses x2l
    float* out1 = (float*)d_out;
    float* out2 = out1 + (size_t)BB * NN * DD;
    // partial stats scratch in d_out (dead before gemm_pv writes it)
    float* rp_max = (float*)d_out;            // [32][4][512]
    float* rp_sum = rp_max + 65536;
    float* cp_max = rp_sum + 65536;           // [32][8][512]
    float* cp_sum = cp_max + 131072;

    convert_split_t<<<4096, 256, 0, stream>>>(x1, x2, x1h, x1l, x1hT, x2h, x2l, x2hT);
    gemm_align<<<512, 512, 0, stream>>>(x1h, x1l, x2h, x2l, mask1, mask2, alg,
                                        rp_max, rp_sum, cp_max, cp_sum);
    combine_stats<<<128, 256, 0, stream>>>(rp_max, rp_sum, cp_max, cp_sum,
                                           rowmax, rowinv, colmax, colinv);
    apply_softmax<<<2048, 256, 0, stream>>>(alg, mask1, mask2, rowmax, rowinv,
                                            colmax, colinv, attn12, attn21);
    gemm_pv<<<1024, 256, 0, stream>>>(attn12, x2hT, out1);
    gemm_pv<<<1024, 256, 0, stream>>>(attn21, x1hT, out2);
}

// Round 7
// 422.479 us; speedup vs baseline: 1.0868x; 1.0065x over previous
//
#include <hip/hip_runtime.h>
#include <hip/hip_bf16.h>

#define BB 32
#define NN 512
#define MM 512
#define DD 1024

typedef __attribute__((ext_vector_type(8))) short short8;
typedef __attribute__((ext_vector_type(4))) float f32x4;

#define ASYNC_COPY16(g, l) \
    __builtin_amdgcn_global_load_lds((__attribute__((address_space(1))) void*)(g), \
                                     (__attribute__((address_space(3))) void*)(l), 16, 0, 0)

__device__ inline unsigned short f2bf(float f) {
    unsigned int u = __float_as_uint(f);
    u += 0x7fffu + ((u >> 16) & 1u);
    return (unsigned short)(u >> 16);
}

#define SPLIT1(vv, hh, ll) { unsigned short h_ = f2bf(vv); \
    float hf_ = __uint_as_float((unsigned int)h_ << 16); \
    hh = h_; ll = f2bf((vv) - hf_); }

// ---------------------------------------------------------------------------
// K0: fused split-convert + transpose. 128(r) x 64(c) tiles, one source per
// block (grid 4096). LDS tile column-major (T[c][r], stride 130).
// STORE-AFTER-BARRIER restructure: phase 1 = load + split + LDS write only
// (split results kept in registers); the one __syncthreads then waits only
// on loads/LDS (no stores pending -> no vmcnt store-drain stall); ALL global
// stores (h, l, hT) issue after the barrier with no further sync.
// ---------------------------------------------------------------------------
__global__ __launch_bounds__(256) void convert_split_t(
    const float* __restrict__ x1, const float* __restrict__ x2,
    unsigned short* __restrict__ x1h, unsigned short* __restrict__ x1l,
    unsigned short* __restrict__ x1hT,
    unsigned short* __restrict__ x2h, unsigned short* __restrict__ x2l,
    unsigned short* __restrict__ x2hT) {
    int bid = blockIdx.x;
    const float* src; unsigned short *h, *l, *hT;
    if (bid < 2048) { src = x1; h = x1h; l = x1l; hT = x1hT; }
    else            { src = x2; h = x2h; l = x2l; hT = x2hT; bid -= 2048; }
    int b = bid >> 6; int rem = bid & 63;
    int r0 = (rem >> 4) * 128, c0 = (rem & 15) * 64;
    __shared__ unsigned short T[64 * 130];   // T[c][r], stride 130
    int t = threadIdx.x;
    int i = t >> 4, j4 = (t & 15) * 4;
    ushort4 HH[8], LL[8];
#pragma unroll
    for (int p = 0; p < 8; ++p) {
        int r = i + p * 16;
        size_t off = ((size_t)b * 512 + r0 + r) * 1024 + c0 + j4;
        float4 v = *(const float4*)&src[off];
        ushort4 hh, ll;
        SPLIT1(v.x, hh.x, ll.x) SPLIT1(v.y, hh.y, ll.y)
        SPLIT1(v.z, hh.z, ll.z) SPLIT1(v.w, hh.w, ll.w)
        HH[p] = hh; LL[p] = ll;
        T[(j4 + 0) * 130 + r] = hh.x;
        T[(j4 + 1) * 130 + r] = hh.y;
        T[(j4 + 2) * 130 + r] = hh.z;
        T[(j4 + 3) * 130 + r] = hh.w;
    }
    __syncthreads();   // waits loads + LDS only; zero stores outstanding
#pragma unroll
    for (int p = 0; p < 8; ++p) {
        int r = i + p * 16;
        size_t off = ((size_t)b * 512 + r0 + r) * 1024 + c0 + j4;
        *(ushort4*)&h[off] = HH[p];
        *(ushort4*)&l[off] = LL[p];
    }
    int rr = (t & 31) * 4;      // 0..124
    int cb = t >> 5;            // 0..7
#pragma unroll
    for (int pp = 0; pp < 8; ++pp) {
        int c = cb + pp * 8;    // 0..63
        uint2 o;
        o.x = *(const unsigned int*)&T[c * 130 + rr];
        o.y = *(const unsigned int*)&T[c * 130 + rr + 2];
        *(uint2*)&hT[((size_t)b * 1024 + c0 + c) * 512 + r0 + rr] = o;
    }
}

// ---------------------------------------------------------------------------
// K1: align = x1 . x2^T (split-bf16, 3-term) + fused tile-local softmax
// partial stats. 128(n) x 128(m) tiles, 8 waves (512 thr), grid 512
// (2 blocks/CU, all co-resident). Double-buffered LDS prefetch (T3-min):
// stage tile k+1 while MFMAing tile k; one barrier per K-step.
// Each wave: 64n x 32m (4x2 frags of 16x16x32).
// ---------------------------------------------------------------------------
__global__ __launch_bounds__(512, 4) void gemm_align(
    const unsigned short* __restrict__ x1h, const unsigned short* __restrict__ x1l,
    const unsigned short* __restrict__ x2h, const unsigned short* __restrict__ x2l,
    const int* __restrict__ mask1, const int* __restrict__ mask2,
    float* __restrict__ alg,
    float* __restrict__ rp_max, float* __restrict__ rp_sum,
    float* __restrict__ cp_max, float* __restrict__ cp_sum) {
    // per buffer: Ah[128][32] | Al | Bh | Bl = 32KB; x2 buffers = 64KB
    __shared__ unsigned short S[2][16384];
    int bid = blockIdx.x;
    int nb = (bid & 7) * 64 + (bid >> 3);    // XCD batch-affinity swizzle (512 = 8*64)
    int b = nb >> 4; int tl = nb & 15;
    int nt = tl >> 2, mt = tl & 3;
    int n0 = nt * 128, m0 = mt * 128;
    int t = threadIdx.x; int w = t >> 6; int l = t & 63;
    int lane16 = l & 15, q = l >> 4, q8 = q * 8;
    int wr = (w >> 2) * 64;                  // wave row offset (0 or 64)
    int wc = (w & 3) * 32;                   // wave col offset (0/32/64/96)
    f32x4 acc[4][2];
#pragma unroll
    for (int i = 0; i < 4; ++i)
#pragma unroll
        for (int j = 0; j < 2; ++j) acc[i][j] = (f32x4){0.f, 0.f, 0.f, 0.f};
    // staging: 32 x 1KB wave-instructions per K-step, 4 per wave
    const unsigned short* gs[4];
    int ls[4];
#pragma unroll
    for (int s = 0; s < 4; ++s) {
        int qq = w * 4 + s;                  // 0..31
        int row0 = (qq & 7) * 16;
        const unsigned short* base; int lb;
        if (qq < 8)       { base = x1h + ((size_t)b * 512 + n0) * 1024; lb = 0; }
        else if (qq < 16) { base = x1l + ((size_t)b * 512 + n0) * 1024; lb = 4096; }
        else if (qq < 24) { base = x2h + ((size_t)b * 512 + m0) * 1024; lb = 8192; }
        else              { base = x2l + ((size_t)b * 512 + m0) * 1024; lb = 12288; }
        gs[s] = base + (size_t)(row0 + (l >> 2)) * 1024 + (l & 3) * 8;
        ls[s] = lb + row0 * 32 + l * 8;
    }
    // prologue: stage K-step 0 into buffer 0
#pragma unroll
    for (int s = 0; s < 4; ++s)
        ASYNC_COPY16(gs[s], &S[0][ls[s]]);
    __syncthreads();
    int cur = 0;
    for (int kk = 0; kk < 1024; kk += 32) {
        if (kk + 32 < 1024) {                // prefetch next K-step into other buffer
#pragma unroll
            for (int s = 0; s < 4; ++s)
                ASYNC_COPY16(gs[s] + kk + 32, &S[cur ^ 1][ls[s]]);
        }
        const unsigned short* Sb = S[cur];
        short8 ah[4], al[4], bh[2], bl[2];
#pragma unroll
        for (int i = 0; i < 4; ++i) {
            int off = (wr + i * 16 + lane16) * 32 + q8;
            ah[i] = *(const short8*)&Sb[off];
            al[i] = *(const short8*)&Sb[4096 + off];
        }
#pragma unroll
        for (int j = 0; j < 2; ++j) {
            int off = (wc + j * 16 + lane16) * 32 + q8;
            bh[j] = *(const short8*)&Sb[8192 + off];
            bl[j] = *(const short8*)&Sb[12288 + off];
        }
#pragma unroll
        for (int i = 0; i < 4; ++i)
#pragma unroll
            for (int j = 0; j < 2; ++j) {
                acc[i][j] = __builtin_amdgcn_mfma_f32_16x16x32_bf16(ah[i], bh[j], acc[i][j], 0, 0, 0);
                acc[i][j] = __builtin_amdgcn_mfma_f32_16x16x32_bf16(ah[i], bl[j], acc[i][j], 0, 0, 0);
                acc[i][j] = __builtin_amdgcn_mfma_f32_16x16x32_bf16(al[i], bh[j], acc[i][j], 0, 0, 0);
            }
        __syncthreads();    // drains vmcnt (prefetch landed) + protects buffer reuse
        cur ^= 1;
    }
    // ---- C store ----
    float* ob = alg + ((size_t)b * 512 + n0 + wr) * 512 + m0 + wc;
    int q4 = q * 4;
#pragma unroll
    for (int i = 0; i < 4; ++i)
#pragma unroll
        for (int j = 0; j < 2; ++j)
#pragma unroll
            for (int r = 0; r < 4; ++r)
                ob[(size_t)(i * 16 + q4 + r) * 512 + j * 16 + lane16] = acc[i][j][r];
    // ---- masks ----
    int mk2[2];
#pragma unroll
    for (int j = 0; j < 2; ++j) mk2[j] = mask2[b * 512 + m0 + wc + j * 16 + lane16];
    int mk1r[4][4];
#pragma unroll
    for (int i = 0; i < 4; ++i)
#pragma unroll
        for (int r = 0; r < 4; ++r) mk1r[i][r] = mask1[b * 512 + n0 + wr + i * 16 + q4 + r];
    // ---- col partials (this wave's 64 n-rows, per m-col); 64-row groups keep
    //      cp granularity at 8 per batch, so combine_stats is unchanged ----
#pragma unroll
    for (int j = 0; j < 2; ++j) {
        float cm = -3.0e38f;
#pragma unroll
        for (int i = 0; i < 4; ++i)
#pragma unroll
            for (int r = 0; r < 4; ++r)
                if (mk1r[i][r]) cm = fmaxf(cm, acc[i][j][r]);
        cm = fmaxf(cm, __shfl_xor(cm, 16));
        cm = fmaxf(cm, __shfl_xor(cm, 32));
        float cs = 0.f;
#pragma unroll
        for (int i = 0; i < 4; ++i)
#pragma unroll
            for (int r = 0; r < 4; ++r)
                cs += mk1r[i][r] ? __expf(acc[i][j][r] - cm) : 0.f;
        cs += __shfl_xor(cs, 16);
        cs += __shfl_xor(cs, 32);
        if (q == 0) {
            size_t o = ((size_t)b * 8 + nt * 2 + (w >> 2)) * 512 + m0 + wc + j * 16 + lane16;
            cp_max[o] = cm;
            cp_sum[o] = cs;
        }
    }
    // ---- row partials (this wave's 32 m-cols per n-row); combine the 4 waves
    //      sharing a wave-row in LDS. rp granularity 4 per batch (unchanged). ----
    float* rmS = (float*)&S[0][0];     // [8][64]
    float* rsS = rmS + 512;            // [8][64]
#pragma unroll
    for (int i = 0; i < 4; ++i)
#pragma unroll
        for (int r = 0; r < 4; ++r) {
            float v0 = acc[i][0][r], v1 = acc[i][1][r];
            float rm = fmaxf(mk2[0] ? v0 : -3.0e38f, mk2[1] ? v1 : -3.0e38f);
            rm = fmaxf(rm, __shfl_xor(rm, 1));
            rm = fmaxf(rm, __shfl_xor(rm, 2));
            rm = fmaxf(rm, __shfl_xor(rm, 4));
            rm = fmaxf(rm, __shfl_xor(rm, 8));
            float rs = (mk2[0] ? __expf(v0 - rm) : 0.f) + (mk2[1] ? __expf(v1 - rm) : 0.f);
            rs += __shfl_xor(rs, 1);
            rs += __shfl_xor(rs, 2);
            rs += __shfl_xor(rs, 4);
            rs += __shfl_xor(rs, 8);
            if (lane16 == 0) {
                int row = i * 16 + q4 + r;
                rmS[w * 64 + row] = rm;
                rsS[w * 64 + row] = rs;
            }
        }
    __syncthreads();
    if (t < 128) {
        int grp = t >> 6, rloc = t & 63;
        float M = -3.0e38f;
#pragma unroll
        for (int ww = 0; ww < 4; ++ww) M = fmaxf(M, rmS[(grp * 4 + ww) * 64 + rloc]);
        float Ssum = 0.f;
#pragma unroll
        for (int ww = 0; ww < 4; ++ww)
            Ssum += rsS[(grp * 4 + ww) * 64 + rloc] * __expf(rmS[(grp * 4 + ww) * 64 + rloc] - M);
        size_t o = ((size_t)b * 4 + mt) * 512 + n0 + t;
        rp_max[o] = M;
        rp_sum[o] = Ssum;
    }
}

// ---------------------------------------------------------------------------
// K2: combine partials -> rowmax/rowinv (per b,n) and colmax/colinv (per b,m)
// ---------------------------------------------------------------------------
__global__ __launch_bounds__(256) void combine_stats(
    const float* __restrict__ rp_max, const float* __restrict__ rp_sum,
    const float* __restrict__ cp_max, const float* __restrict__ cp_sum,
    float* __restrict__ rowmax, float* __restrict__ rowinv,
    float* __restrict__ colmax, float* __restrict__ colinv) {
    int idx = blockIdx.x * 256 + threadIdx.x;   // 0..32767
    if (idx < 16384) {
        int b = idx >> 9, n = idx & 511;
        float M = -3.0e38f;
#pragma unroll
        for (int tt = 0; tt < 4; ++tt) M = fmaxf(M, rp_max[((size_t)b * 4 + tt) * 512 + n]);
        float S = 0.f;
#pragma unroll
        for (int tt = 0; tt < 4; ++tt) {
            size_t o = ((size_t)b * 4 + tt) * 512 + n;
            S += rp_sum[o] * __expf(rp_max[o] - M);
        }
        rowmax[idx] = M;
        rowinv[idx] = 1.0f / S;
    } else {
        int id2 = idx - 16384;
        int b = id2 >> 9, m = id2 & 511;
        float M = -3.0e38f;
#pragma unroll
        for (int tt = 0; tt < 8; ++tt) M = fmaxf(M, cp_max[((size_t)b * 8 + tt) * 512 + m]);
        float S = 0.f;
#pragma unroll
        for (int tt = 0; tt < 8; ++tt) {
            size_t o = ((size_t)b * 8 + tt) * 512 + m;
            S += cp_sum[o] * __expf(cp_max[o] - M);
        }
        colmax[id2] = M;
        colinv[id2] = 1.0f / S;
    }
}

// ---------------------------------------------------------------------------
// K3: apply — read align once, write attn12[n][m] and attn21[m][n] (bf16).
// STORE-AFTER-BARRIER: attn12 values computed into registers in phase 1;
// all stores (attn12 + attn21) issue after the one barrier.
// ---------------------------------------------------------------------------
__global__ __launch_bounds__(256) void apply_softmax(
    const float* __restrict__ alg, const int* __restrict__ mask1,
    const int* __restrict__ mask2,
    const float* __restrict__ rowmax, const float* __restrict__ rowinv,
    const float* __restrict__ colmax, const float* __restrict__ colinv,
    unsigned short* __restrict__ attn12, unsigned short* __restrict__ attn21) {
    int bid = blockIdx.x; int b = bid >> 6; int rem = bid & 63;
    int m0 = (rem >> 3) * 64, n0 = (rem & 7) * 64;
    int t = threadIdx.x;
    __shared__ float lds[64 * 65];
    int jj = t & 63; int ii = t >> 6;
    int mk2 = mask2[b * 512 + m0 + jj];
    unsigned short e12[16];
#pragma unroll
    for (int p = 0; p < 16; ++p) {
        int n = ii + p * 4;
        float v = alg[((size_t)b * 512 + n0 + n) * 512 + m0 + jj];
        lds[n * 65 + jj] = v;
        float rm = rowmax[b * 512 + n0 + n];
        float ri = rowinv[b * 512 + n0 + n];
        e12[p] = mk2 ? f2bf(__expf(v - rm) * ri) : (unsigned short)0;
    }
    __syncthreads();   // waits loads + LDS only; no stores outstanding
#pragma unroll
    for (int p = 0; p < 16; ++p) {
        int n = ii + p * 4;
        attn12[((size_t)b * 512 + n0 + n) * 512 + m0 + jj] = e12[p];
    }
    int mk1 = mask1[b * 512 + n0 + jj];
#pragma unroll
    for (int p = 0; p < 16; ++p) {
        int mm = ii + p * 4;
        float cm = colmax[b * 512 + m0 + mm];
        float ci = colinv[b * 512 + m0 + mm];
        float v = lds[jj * 65 + mm];
        unsigned short pv = mk1 ? f2bf(__expf(v - cm) * ci) : (unsigned short)0;
        attn21[((size_t)b * 512 + m0 + mm) * 512 + n0 + jj] = pv;
    }
}

// ---------------------------------------------------------------------------
// K4/K5: out[b][r][d] = sum_k P[b][r][k] * VT[b][d][k]  (bf16 MFMA, async,
// double-buffered prefetch: stage k+1 while MFMAing k; 1 barrier/K-step)
// ---------------------------------------------------------------------------
__global__ __launch_bounds__(256) void gemm_pv(
    const unsigned short* __restrict__ P, const unsigned short* __restrict__ VT,
    float* __restrict__ out) {
    __shared__ unsigned short S[2][2][4096];   // [dbuf][A/B][128*32] = 32KB
    int bid = blockIdx.x;
    int nb = (bid & 7) * 128 + (bid >> 3);  // XCD batch-affinity swizzle
    int b = nb >> 5; int rem = nb & 31;
    int n0 = (rem >> 3) * 128, d0 = (rem & 7) * 128;
    int t = threadIdx.x; int w = t >> 6; int l = t & 63;
    int lane16 = l & 15, q8 = (l >> 4) * 8;
    int wr = (w >> 1) * 64, wc = (w & 1) * 64;
    f32x4 acc[4][4];
#pragma unroll
    for (int i = 0; i < 4; ++i)
#pragma unroll
        for (int j = 0; j < 4; ++j) acc[i][j] = (f32x4){0.f, 0.f, 0.f, 0.f};
    const unsigned short* gA = P + ((size_t)b * 512 + n0) * 512;
    const unsigned short* gB = VT + ((size_t)b * DD + d0) * 512;
    int w2 = w & 1;
    int side = (w < 2) ? 0 : 1;
    const unsigned short* gp = (w < 2) ? gA : gB;
    const unsigned short* gbase = gp + (size_t)(w2 * 64 + (l >> 2)) * 512 + (l & 3) * 8;
    int lofs = w2 * 2048;
    // prologue: stage K-step 0 into buffer 0
#pragma unroll
    for (int p = 0; p < 4; ++p)
        ASYNC_COPY16(gbase + (size_t)(p * 16) * 512, &S[0][side][lofs + p * 512]);
    __syncthreads();
    int cur = 0;
    for (int kk = 0; kk < 512; kk += 32) {
        if (kk + 32 < 512) {
#pragma unroll
            for (int p = 0; p < 4; ++p)
                ASYNC_COPY16(gbase + (size_t)(p * 16) * 512 + kk + 32,
                             &S[cur ^ 1][side][lofs + p * 512]);
        }
        short8 af[4], bf[4];
#pragma unroll
        for (int i = 0; i < 4; ++i)
            af[i] = *(const short8*)&S[cur][0][(wr + i * 16 + lane16) * 32 + q8];
#pragma unroll
        for (int j = 0; j < 4; ++j)
            bf[j] = *(const short8*)&S[cur][1][(wc + j * 16 + lane16) * 32 + q8];
#pragma unroll
        for (int i = 0; i < 4; ++i)
#pragma unroll
            for (int j = 0; j < 4; ++j)
                acc[i][j] = __builtin_amdgcn_mfma_f32_16x16x32_bf16(af[i], bf[j], acc[i][j], 0, 0, 0);
        __syncthreads();
        cur ^= 1;
    }
    int q4 = (l >> 4) * 4;
#pragma unroll
    for (int i = 0; i < 4; ++i)
#pragma unroll
        for (int j = 0; j < 4; ++j)
#pragma unroll
            for (int r = 0; r < 4; ++r) {
                int rr = n0 + wr + i * 16 + q4 + r;
                int dd = d0 + wc + j * 16 + lane16;
                out[((size_t)b * 512 + rr) * DD + dd] = acc[i][j][r];
            }
}

// ---------------------------------------------------------------------------
// ws layout (224MB): x1h 0 | x2h 32M | x1hT 64M | x2hT 96M | x1l 128M |
//   x2l 160M | alg 192M.  After gemm_align: attn12 @128M (16MB), stats
//   @144M (256KB), attn21 @160M (16MB).  Partials live in d_out scratch
//   (overwritten by gemm_pv afterwards).
// ---------------------------------------------------------------------------
extern "C" void kernel_launch(void* const* d_in, const int* in_sizes, int n_in,
                              void* d_out, int out_size, void* d_ws, size_t ws_size,
                              hipStream_t stream) {
    const float* x1 = (const float*)d_in[0];
    const float* x2 = (const float*)d_in[1];
    const int* mask1 = (const int*)d_in[2];
    const int* mask2 = (const int*)d_in[3];
    char* ws = (char*)d_ws;
    unsigned short* x1h  = (unsigned short*)(ws);
    unsigned short* x2h  = (unsigned short*)(ws + 33554432UL);
    unsigned short* x1hT = (unsigned short*)(ws + 67108864UL);
    unsigned short* x2hT = (unsigned short*)(ws + 100663296UL);
    unsigned short* x1l  = (unsigned short*)(ws + 134217728UL);
    unsigned short* x2l  = (unsigned short*)(ws + 167772160UL);
    float* alg           = (float*)(ws + 201326592UL);
    unsigned short* attn12 = (unsigned short*)(ws + 134217728UL);  // reuses x1l
    float* rowmax        = (float*)(ws + 150994944UL);             // @144MB
    float* rowinv        = (float*)(ws + 151060480UL);
    float* colmax        = (float*)(ws + 151126016UL);
    float* colinv        = (float*)(ws + 151191552UL);
    unsigned short* attn21 = (unsigned short*)(ws + 167772160UL);  // reuses x2l
    float* out1 = (float*)d_out;
    float* out2 = out1 + (size_t)BB * NN * DD;
    // partial stats scratch in d_out (dead before gemm_pv writes it)
    float* rp_max = (float*)d_out;            // [32][4][512]
    float* rp_sum = rp_max + 65536;
    float* cp_max = rp_sum + 65536;           // [32][8][512]
    float* cp_sum = cp_max + 131072;

    convert_split_t<<<4096, 256, 0, stream>>>(x1, x2, x1h, x1l, x1hT, x2h, x2l, x2hT);
    gemm_align<<<512, 512, 0, stream>>>(x1h, x1l, x2h, x2l, mask1, mask2, alg,
                                        rp_max, rp_sum, cp_max, cp_sum);
    combine_stats<<<128, 256, 0, stream>>>(rp_max, rp_sum, cp_max, cp_sum,
                                           rowmax, rowinv, colmax, colinv);
    apply_softmax<<<2048, 256, 0, stream>>>(alg, mask1, mask2, rowmax, rowinv,
                                            colmax, colinv, attn12, attn21);
    gemm_pv<<<1024, 256, 0, stream>>>(attn12, x2hT, out1);
    gemm_pv<<<1024, 256, 0, stream>>>(attn21, x1hT, out2);
}

// Round 10
// 408.653 us; speedup vs baseline: 1.1236x; 1.0338x over previous
//
#include <hip/hip_runtime.h>
#include <hip/hip_bf16.h>

#define BB 32
#define NN 512
#define MM 512
#define DD 1024

typedef __attribute__((ext_vector_type(8))) short short8;
typedef __attribute__((ext_vector_type(4))) float f32x4;

#define ASYNC_COPY16(g, l) \
    __builtin_amdgcn_global_load_lds((__attribute__((address_space(1))) void*)(g), \
                                     (__attribute__((address_space(3))) void*)(l), 16, 0, 0)

__device__ inline unsigned short f2bf(float f) {
    unsigned int u = __float_as_uint(f);
    u += 0x7fffu + ((u >> 16) & 1u);
    return (unsigned short)(u >> 16);
}

#define SPLIT1(vv, hh, ll) { unsigned short h_ = f2bf(vv); \
    float hf_ = __uint_as_float((unsigned int)h_ << 16); \
    hh = h_; ll = f2bf((vv) - hf_); }

// ---------------------------------------------------------------------------
// K0: pure streaming split-convert (no transpose, no LDS, no barrier).
// 193MB traffic (65 fetch + 128 write) vs fused version's 257MB.
// ---------------------------------------------------------------------------
__global__ __launch_bounds__(256) void convert_split(
    const float* __restrict__ x1, const float* __restrict__ x2,
    unsigned short* __restrict__ x1h, unsigned short* __restrict__ x1l,
    unsigned short* __restrict__ x2h, unsigned short* __restrict__ x2l) {
    size_t g = (size_t)blockIdx.x * 256 + threadIdx.x;   // 0..2097151
#pragma unroll
    for (int r = 0; r < 2; ++r) {
        size_t idx = g + (size_t)r * 2097152;            // float4 index, < 4194304
        float4 v = ((const float4*)x1)[idx];
        ushort4 hh, ll;
        SPLIT1(v.x, hh.x, ll.x) SPLIT1(v.y, hh.y, ll.y)
        SPLIT1(v.z, hh.z, ll.z) SPLIT1(v.w, hh.w, ll.w)
        ((ushort4*)x1h)[idx] = hh;
        ((ushort4*)x1l)[idx] = ll;
        float4 u = ((const float4*)x2)[idx];
        ushort4 hh2, ll2;
        SPLIT1(u.x, hh2.x, ll2.x) SPLIT1(u.y, hh2.y, ll2.y)
        SPLIT1(u.z, hh2.z, ll2.z) SPLIT1(u.w, hh2.w, ll2.w)
        ((ushort4*)x2h)[idx] = hh2;
        ((ushort4*)x2l)[idx] = ll2;
    }
}

// ---------------------------------------------------------------------------
// K1: align GEMM + fused partial softmax stats (unchanged, R7-passing).
// ---------------------------------------------------------------------------
__global__ __launch_bounds__(512, 4) void gemm_align(
    const unsigned short* __restrict__ x1h, const unsigned short* __restrict__ x1l,
    const unsigned short* __restrict__ x2h, const unsigned short* __restrict__ x2l,
    const int* __restrict__ mask1, const int* __restrict__ mask2,
    float* __restrict__ alg,
    float* __restrict__ rp_max, float* __restrict__ rp_sum,
    float* __restrict__ cp_max, float* __restrict__ cp_sum) {
    __shared__ unsigned short S[2][16384];
    int bid = blockIdx.x;
    int nb = (bid & 7) * 64 + (bid >> 3);    // XCD batch-affinity swizzle
    int b = nb >> 4; int tl = nb & 15;
    int nt = tl >> 2, mt = tl & 3;
    int n0 = nt * 128, m0 = mt * 128;
    int t = threadIdx.x; int w = t >> 6; int l = t & 63;
    int lane16 = l & 15, q = l >> 4, q8 = q * 8;
    int wr = (w >> 2) * 64;
    int wc = (w & 3) * 32;
    f32x4 acc[4][2];
#pragma unroll
    for (int i = 0; i < 4; ++i)
#pragma unroll
        for (int j = 0; j < 2; ++j) acc[i][j] = (f32x4){0.f, 0.f, 0.f, 0.f};
    const unsigned short* gs[4];
    int ls[4];
#pragma unroll
    for (int s = 0; s < 4; ++s) {
        int qq = w * 4 + s;
        int row0 = (qq & 7) * 16;
        const unsigned short* base; int lb;
        if (qq < 8)       { base = x1h + ((size_t)b * 512 + n0) * 1024; lb = 0; }
        else if (qq < 16) { base = x1l + ((size_t)b * 512 + n0) * 1024; lb = 4096; }
        else if (qq < 24) { base = x2h + ((size_t)b * 512 + m0) * 1024; lb = 8192; }
        else              { base = x2l + ((size_t)b * 512 + m0) * 1024; lb = 12288; }
        gs[s] = base + (size_t)(row0 + (l >> 2)) * 1024 + (l & 3) * 8;
        ls[s] = lb + row0 * 32 + l * 8;
    }
#pragma unroll
    for (int s = 0; s < 4; ++s)
        ASYNC_COPY16(gs[s], &S[0][ls[s]]);
    __syncthreads();
    int cur = 0;
    for (int kk = 0; kk < 1024; kk += 32) {
        if (kk + 32 < 1024) {
#pragma unroll
            for (int s = 0; s < 4; ++s)
                ASYNC_COPY16(gs[s] + kk + 32, &S[cur ^ 1][ls[s]]);
        }
        const unsigned short* Sb = S[cur];
        short8 ah[4], al[4], bh[2], bl[2];
#pragma unroll
        for (int i = 0; i < 4; ++i) {
            int off = (wr + i * 16 + lane16) * 32 + q8;
            ah[i] = *(const short8*)&Sb[off];
            al[i] = *(const short8*)&Sb[4096 + off];
        }
#pragma unroll
        for (int j = 0; j < 2; ++j) {
            int off = (wc + j * 16 + lane16) * 32 + q8;
            bh[j] = *(const short8*)&Sb[8192 + off];
            bl[j] = *(const short8*)&Sb[12288 + off];
        }
#pragma unroll
        for (int i = 0; i < 4; ++i)
#pragma unroll
            for (int j = 0; j < 2; ++j) {
                acc[i][j] = __builtin_amdgcn_mfma_f32_16x16x32_bf16(ah[i], bh[j], acc[i][j], 0, 0, 0);
                acc[i][j] = __builtin_amdgcn_mfma_f32_16x16x32_bf16(ah[i], bl[j], acc[i][j], 0, 0, 0);
                acc[i][j] = __builtin_amdgcn_mfma_f32_16x16x32_bf16(al[i], bh[j], acc[i][j], 0, 0, 0);
            }
        __syncthreads();
        cur ^= 1;
    }
    float* ob = alg + ((size_t)b * 512 + n0 + wr) * 512 + m0 + wc;
    int q4 = q * 4;
#pragma unroll
    for (int i = 0; i < 4; ++i)
#pragma unroll
        for (int j = 0; j < 2; ++j)
#pragma unroll
            for (int r = 0; r < 4; ++r)
                ob[(size_t)(i * 16 + q4 + r) * 512 + j * 16 + lane16] = acc[i][j][r];
    int mk2[2];
#pragma unroll
    for (int j = 0; j < 2; ++j) mk2[j] = mask2[b * 512 + m0 + wc + j * 16 + lane16];
    int mk1r[4][4];
#pragma unroll
    for (int i = 0; i < 4; ++i)
#pragma unroll
        for (int r = 0; r < 4; ++r) mk1r[i][r] = mask1[b * 512 + n0 + wr + i * 16 + q4 + r];
#pragma unroll
    for (int j = 0; j < 2; ++j) {
        float cm = -3.0e38f;
#pragma unroll
        for (int i = 0; i < 4; ++i)
#pragma unroll
            for (int r = 0; r < 4; ++r)
                if (mk1r[i][r]) cm = fmaxf(cm, acc[i][j][r]);
        cm = fmaxf(cm, __shfl_xor(cm, 16));
        cm = fmaxf(cm, __shfl_xor(cm, 32));
        float cs = 0.f;
#pragma unroll
        for (int i = 0; i < 4; ++i)
#pragma unroll
            for (int r = 0; r < 4; ++r)
                cs += mk1r[i][r] ? __expf(acc[i][j][r] - cm) : 0.f;
        cs += __shfl_xor(cs, 16);
        cs += __shfl_xor(cs, 32);
        if (q == 0) {
            size_t o = ((size_t)b * 8 + nt * 2 + (w >> 2)) * 512 + m0 + wc + j * 16 + lane16;
            cp_max[o] = cm;
            cp_sum[o] = cs;
        }
    }
    float* rmS = (float*)&S[0][0];
    float* rsS = rmS + 512;
#pragma unroll
    for (int i = 0; i < 4; ++i)
#pragma unroll
        for (int r = 0; r < 4; ++r) {
            float v0 = acc[i][0][r], v1 = acc[i][1][r];
            float rm = fmaxf(mk2[0] ? v0 : -3.0e38f, mk2[1] ? v1 : -3.0e38f);
            rm = fmaxf(rm, __shfl_xor(rm, 1));
            rm = fmaxf(rm, __shfl_xor(rm, 2));
            rm = fmaxf(rm, __shfl_xor(rm, 4));
            rm = fmaxf(rm, __shfl_xor(rm, 8));
            float rs = (mk2[0] ? __expf(v0 - rm) : 0.f) + (mk2[1] ? __expf(v1 - rm) : 0.f);
            rs += __shfl_xor(rs, 1);
            rs += __shfl_xor(rs, 2);
            rs += __shfl_xor(rs, 4);
            rs += __shfl_xor(rs, 8);
            if (lane16 == 0) {
                int row = i * 16 + q4 + r;
                rmS[w * 64 + row] = rm;
                rsS[w * 64 + row] = rs;
            }
        }
    __syncthreads();
    if (t < 128) {
        int grp = t >> 6, rloc = t & 63;
        float M = -3.0e38f;
#pragma unroll
        for (int ww = 0; ww < 4; ++ww) M = fmaxf(M, rmS[(grp * 4 + ww) * 64 + rloc]);
        float Ssum = 0.f;
#pragma unroll
        for (int ww = 0; ww < 4; ++ww)
            Ssum += rsS[(grp * 4 + ww) * 64 + rloc] * __expf(rmS[(grp * 4 + ww) * 64 + rloc] - M);
        size_t o = ((size_t)b * 4 + mt) * 512 + n0 + t;
        rp_max[o] = M;
        rp_sum[o] = Ssum;
    }
}

// ---------------------------------------------------------------------------
// K2: combine partials (unchanged)
// ---------------------------------------------------------------------------
__global__ __launch_bounds__(256) void combine_stats(
    const float* __restrict__ rp_max, const float* __restrict__ rp_sum,
    const float* __restrict__ cp_max, const float* __restrict__ cp_sum,
    float* __restrict__ rowmax, float* __restrict__ rowinv,
    float* __restrict__ colmax, float* __restrict__ colinv) {
    int idx = blockIdx.x * 256 + threadIdx.x;
    if (idx < 16384) {
        int b = idx >> 9, n = idx & 511;
        float M = -3.0e38f;
#pragma unroll
        for (int tt = 0; tt < 4; ++tt) M = fmaxf(M, rp_max[((size_t)b * 4 + tt) * 512 + n]);
        float S = 0.f;
#pragma unroll
        for (int tt = 0; tt < 4; ++tt) {
            size_t o = ((size_t)b * 4 + tt) * 512 + n;
            S += rp_sum[o] * __expf(rp_max[o] - M);
        }
        rowmax[idx] = M;
        rowinv[idx] = 1.0f / S;
    } else {
        int id2 = idx - 16384;
        int b = id2 >> 9, m = id2 & 511;
        float M = -3.0e38f;
#pragma unroll
        for (int tt = 0; tt < 8; ++tt) M = fmaxf(M, cp_max[((size_t)b * 8 + tt) * 512 + m]);
        float S = 0.f;
#pragma unroll
        for (int tt = 0; tt < 8; ++tt) {
            size_t o = ((size_t)b * 8 + tt) * 512 + m;
            S += cp_sum[o] * __expf(cp_max[o] - M);
        }
        colmax[id2] = M;
        colinv[id2] = 1.0f / S;
    }
}

// ---------------------------------------------------------------------------
// K3: apply softmax (unchanged, R7-passing store-after-barrier version)
// ---------------------------------------------------------------------------
__global__ __launch_bounds__(256) void apply_softmax(
    const float* __restrict__ alg, const int* __restrict__ mask1,
    const int* __restrict__ mask2,
    const float* __restrict__ rowmax, const float* __restrict__ rowinv,
    const float* __restrict__ colmax, const float* __restrict__ colinv,
    unsigned short* __restrict__ attn12, unsigned short* __restrict__ attn21) {
    int bid = blockIdx.x; int b = bid >> 6; int rem = bid & 63;
    int m0 = (rem >> 3) * 64, n0 = (rem & 7) * 64;
    int t = threadIdx.x;
    __shared__ float lds[64 * 65];
    int jj = t & 63; int ii = t >> 6;
    int mk2 = mask2[b * 512 + m0 + jj];
    unsigned short e12[16];
#pragma unroll
    for (int p = 0; p < 16; ++p) {
        int n = ii + p * 4;
        float v = alg[((size_t)b * 512 + n0 + n) * 512 + m0 + jj];
        lds[n * 65 + jj] = v;
        float rm = rowmax[b * 512 + n0 + n];
        float ri = rowinv[b * 512 + n0 + n];
        e12[p] = mk2 ? f2bf(__expf(v - rm) * ri) : (unsigned short)0;
    }
    __syncthreads();
#pragma unroll
    for (int p = 0; p < 16; ++p) {
        int n = ii + p * 4;
        attn12[((size_t)b * 512 + n0 + n) * 512 + m0 + jj] = e12[p];
    }
    int mk1 = mask1[b * 512 + n0 + jj];
#pragma unroll
    for (int p = 0; p < 16; ++p) {
        int mm = ii + p * 4;
        float cm = colmax[b * 512 + m0 + mm];
        float ci = colinv[b * 512 + m0 + mm];
        float v = lds[jj * 65 + mm];
        unsigned short pv = mk1 ? f2bf(__expf(v - cm) * ci) : (unsigned short)0;
        attn21[((size_t)b * 512 + m0 + mm) * 512 + n0 + jj] = pv;
    }
}

// ---------------------------------------------------------------------------
// K4/K5: out[b][r][d] = sum_m P[b][r][m] * V[b][m][d] -- V consumed k-major.
// A (P rows) staged via global_load_lds into [128n][32m] as before.
// B: reg-staged transpose -- coalesced short8 loads from V rows, ds_write_b32
// into padded [32m][130] bf16 tile (pad 130 elems = 65 words/row === 1 mod 32:
// staged writes ~2 lanes/bank (free), frag u16 reads fully bank-spread:
// q-groups at +8*65=520w === 8 mod 32, lane16 pairs share words).
// B fragments read as 8 x ds_read_u16 per frag (m=q8..q8+7 at fixed d).
// ---------------------------------------------------------------------------
__global__ __launch_bounds__(256) void gemm_pv(
    const unsigned short* __restrict__ P, const unsigned short* __restrict__ V,
    float* __restrict__ out) {
    __shared__ unsigned short SA[2][4096];       // [128n][32m] bf16, 8KB/buf
    __shared__ unsigned int   SB[2][32 * 65];    // [32m][130 u16] padded, 8.3KB/buf
    int bid = blockIdx.x;
    int nb = (bid & 7) * 128 + (bid >> 3);  // XCD batch-affinity swizzle
    int b = nb >> 5; int rem = nb & 31;
    int n0 = (rem >> 3) * 128, d0 = (rem & 7) * 128;
    int t = threadIdx.x; int w = t >> 6; int l = t & 63;
    int lane16 = l & 15, q = l >> 4, q8 = q * 8;
    int wr = (w >> 1) * 64, wc = (w & 1) * 64;
    f32x4 acc[4][4];
#pragma unroll
    for (int i = 0; i < 4; ++i)
#pragma unroll
        for (int j = 0; j < 4; ++j) acc[i][j] = (f32x4){0.f, 0.f, 0.f, 0.f};
    const unsigned short* gA = P + ((size_t)b * 512 + n0) * 512;
    // ---- A staging (gload_lds, linear [128][32]) : 2 instrs/wave ----
    const unsigned short* gsA[2];
    int ldsa[2];
#pragma unroll
    for (int s = 0; s < 2; ++s) {
        int a = w * 2 + s;                   // 0..7 panels of 16 rows
        gsA[s] = gA + (size_t)(a * 16 + (l >> 2)) * 512 + (l & 3) * 8;
        ldsa[s] = a * 512 + l * 8;
    }
    // ---- B staging (reg-staged transpose) : 2 slots/thread ----
    int dch = l & 15;                        // 16B d-chunk index
    int mloc[2]; mloc[0] = w * 4 + q; mloc[1] = mloc[0] + 16;
    const unsigned short* gB0[2];
#pragma unroll
    for (int s = 0; s < 2; ++s)
        gB0[s] = V + (size_t)b * 524288 + (size_t)mloc[s] * 1024 + d0 + dch * 8;
    union U8 { short8 s; unsigned int u[4]; };
    // prologue: load + write B(0), issue A(0)
    U8 bv[2];
#pragma unroll
    for (int s = 0; s < 2; ++s) bv[s].s = *(const short8*)gB0[s];
#pragma unroll
    for (int s = 0; s < 2; ++s)
        ASYNC_COPY16(gsA[s], &SA[0][ldsa[s]]);
#pragma unroll
    for (int s = 0; s < 2; ++s)
#pragma unroll
        for (int c = 0; c < 4; ++c)
            SB[0][mloc[s] * 65 + dch * 4 + c] = bv[s].u[c];
    __syncthreads();
    int cur = 0;
    for (int kk = 0; kk < 512; kk += 32) {
        int more = (kk + 32 < 512);
        if (more) {   // issue next-tile loads early (regs + A DMA)
#pragma unroll
            for (int s = 0; s < 2; ++s) bv[s].s = *(const short8*)(gB0[s] + (size_t)(kk + 32) * 1024);
#pragma unroll
            for (int s = 0; s < 2; ++s)
                ASYNC_COPY16(gsA[s] + kk + 32, &SA[cur ^ 1][ldsa[s]]);
        }
        // ---- fragments ----
        short8 af[4];
#pragma unroll
        for (int i = 0; i < 4; ++i)
            af[i] = *(const short8*)&SA[cur][(wr + i * 16 + lane16) * 32 + q8];
        const unsigned short* Bs = (const unsigned short*)SB[cur];
        short8 bf[4];
#pragma unroll
        for (int j = 0; j < 4; ++j) {
            int col = wc + j * 16 + lane16;
#pragma unroll
            for (int e = 0; e < 8; ++e)
                bf[j][e] = (short)Bs[(q8 + e) * 130 + col];
        }
#pragma unroll
        for (int i = 0; i < 4; ++i)
#pragma unroll
            for (int j = 0; j < 4; ++j)
                acc[i][j] = __builtin_amdgcn_mfma_f32_16x16x32_bf16(af[i], bf[j], acc[i][j], 0, 0, 0);
        if (more) {   // write next B tile after compute (T14 split)
#pragma unroll
            for (int s = 0; s < 2; ++s)
#pragma unroll
                for (int c = 0; c < 4; ++c)
                    SB[cur ^ 1][mloc[s] * 65 + dch * 4 + c] = bv[s].u[c];
        }
        __syncthreads();
        cur ^= 1;
    }
    int q4 = q * 4;
#pragma unroll
    for (int i = 0; i < 4; ++i)
#pragma unroll
        for (int j = 0; j < 4; ++j)
#pragma unroll
            for (int r = 0; r < 4; ++r) {
                int rr = n0 + wr + i * 16 + q4 + r;
                int dd = d0 + wc + j * 16 + lane16;
                out[((size_t)b * 512 + rr) * DD + dd] = acc[i][j][r];
            }
}

// ---------------------------------------------------------------------------
// ws layout (224MB): x1h 0 | x2h 32M | (64M..128M unused) | x1l 128M |
//   x2l 160M | alg 192M.  After gemm_align: attn12 @128M (reuses x1l), stats
//   @144M, attn21 @160M (reuses x2l).  Partial stats live in d_out scratch.
//   gemm_pv reads x1h/x2h directly (k-major) -- no hT arrays.
// ---------------------------------------------------------------------------
extern "C" void kernel_launch(void* const* d_in, const int* in_sizes, int n_in,
                              void* d_out, int out_size, void* d_ws, size_t ws_size,
                              hipStream_t stream) {
    const float* x1 = (const float*)d_in[0];
    const float* x2 = (const float*)d_in[1];
    const int* mask1 = (const int*)d_in[2];
    const int* mask2 = (const int*)d_in[3];
    char* ws = (char*)d_ws;
    unsigned short* x1h  = (unsigned short*)(ws);
    unsigned short* x2h  = (unsigned short*)(ws + 33554432UL);
    unsigned short* x1l  = (unsigned short*)(ws + 134217728UL);
    unsigned short* x2l  = (unsigned short*)(ws + 167772160UL);
    float* alg           = (float*)(ws + 201326592UL);
    unsigned short* attn12 = (unsigned short*)(ws + 134217728UL);  // reuses x1l
    float* rowmax        = (float*)(ws + 150994944UL);             // @144MB
    float* rowinv        = (float*)(ws + 151060480UL);
    float* colmax        = (float*)(ws + 151126016UL);
    float* colinv        = (float*)(ws + 151191552UL);
    unsigned short* attn21 = (unsigned short*)(ws + 167772160UL);  // reuses x2l
    float* out1 = (float*)d_out;
    float* out2 = out1 + (size_t)BB * NN * DD;
    float* rp_max = (float*)d_out;            // [32][4][512]
    float* rp_sum = rp_max + 65536;
    float* cp_max = rp_sum + 65536;           // [32][8][512]
    float* cp_sum = cp_max + 131072;

    convert_split<<<8192, 256, 0, stream>>>(x1, x2, x1h, x1l, x2h, x2l);
    gemm_align<<<512, 512, 0, stream>>>(x1h, x1l, x2h, x2l, mask1, mask2, alg,
                                        rp_max, rp_sum, cp_max, cp_sum);
    combine_stats<<<128, 256, 0, stream>>>(rp_max, rp_sum, cp_max, cp_sum,
                                           rowmax, rowinv, colmax, colinv);
    apply_softmax<<<2048, 256, 0, stream>>>(alg, mask1, mask2, rowmax, rowinv,
                                            colmax, colinv, attn12, attn21);
    gemm_pv<<<1024, 256, 0, stream>>>(attn12, x2h, out1);
    gemm_pv<<<1024, 256, 0, stream>>>(attn21, x1h, out2);
}

// Round 11
// 381.209 us; speedup vs baseline: 1.2045x; 1.0720x over previous
//
#include <hip/hip_runtime.h>
#include <hip/hip_bf16.h>

#define BB 32
#define NN 512
#define MM 512
#define DD 1024

typedef __attribute__((ext_vector_type(8))) short short8;
typedef __attribute__((ext_vector_type(4))) float f32x4;

#define ASYNC_COPY16(g, l) \
    __builtin_amdgcn_global_load_lds((__attribute__((address_space(1))) void*)(g), \
                                     (__attribute__((address_space(3))) void*)(l), 16, 0, 0)

__device__ inline unsigned short f2bf(float f) {
    unsigned int u = __float_as_uint(f);
    u += 0x7fffu + ((u >> 16) & 1u);
    return (unsigned short)(u >> 16);
}

#define SPLIT1(vv, hh, ll) { unsigned short h_ = f2bf(vv); \
    float hf_ = __uint_as_float((unsigned int)h_ << 16); \
    hh = h_; ll = f2bf((vv) - hf_); }

// ---------------------------------------------------------------------------
// K0: pure streaming split-convert (no transpose/LDS/barrier). Unchanged R10.
// ---------------------------------------------------------------------------
__global__ __launch_bounds__(256) void convert_split(
    const float* __restrict__ x1, const float* __restrict__ x2,
    unsigned short* __restrict__ x1h, unsigned short* __restrict__ x1l,
    unsigned short* __restrict__ x2h, unsigned short* __restrict__ x2l) {
    size_t g = (size_t)blockIdx.x * 256 + threadIdx.x;
#pragma unroll
    for (int r = 0; r < 2; ++r) {
        size_t idx = g + (size_t)r * 2097152;
        float4 v = ((const float4*)x1)[idx];
        ushort4 hh, ll;
        SPLIT1(v.x, hh.x, ll.x) SPLIT1(v.y, hh.y, ll.y)
        SPLIT1(v.z, hh.z, ll.z) SPLIT1(v.w, hh.w, ll.w)
        ((ushort4*)x1h)[idx] = hh;
        ((ushort4*)x1l)[idx] = ll;
        float4 u = ((const float4*)x2)[idx];
        ushort4 hh2, ll2;
        SPLIT1(u.x, hh2.x, ll2.x) SPLIT1(u.y, hh2.y, ll2.y)
        SPLIT1(u.z, hh2.z, ll2.z) SPLIT1(u.w, hh2.w, ll2.w)
        ((ushort4*)x2h)[idx] = hh2;
        ((ushort4*)x2l)[idx] = ll2;
    }
}

// ---------------------------------------------------------------------------
// K1: align GEMM + fused partial softmax stats. T4 counted-vmcnt K-loop:
// issue prefetch(t+1) -> vmcnt(4) waits ONLY tile-t loads (issued a full
// K-step ago, ~landed) -> raw s_barrier -> compute -> raw s_barrier.
// No vmcnt(0) drain in the main loop (the ~600cy/K-step stall).
// ---------------------------------------------------------------------------
__global__ __launch_bounds__(512, 4) void gemm_align(
    const unsigned short* __restrict__ x1h, const unsigned short* __restrict__ x1l,
    const unsigned short* __restrict__ x2h, const unsigned short* __restrict__ x2l,
    const int* __restrict__ mask1, const int* __restrict__ mask2,
    float* __restrict__ alg,
    float* __restrict__ rp_max, float* __restrict__ rp_sum,
    float* __restrict__ cp_max, float* __restrict__ cp_sum) {
    __shared__ unsigned short S[2][16384];
    int bid = blockIdx.x;
    int nb = (bid & 7) * 64 + (bid >> 3);    // XCD batch-affinity swizzle
    int b = nb >> 4; int tl = nb & 15;
    int nt = tl >> 2, mt = tl & 3;
    int n0 = nt * 128, m0 = mt * 128;
    int t = threadIdx.x; int w = t >> 6; int l = t & 63;
    int lane16 = l & 15, q = l >> 4, q8 = q * 8;
    int wr = (w >> 2) * 64;
    int wc = (w & 3) * 32;
    f32x4 acc[4][2];
#pragma unroll
    for (int i = 0; i < 4; ++i)
#pragma unroll
        for (int j = 0; j < 2; ++j) acc[i][j] = (f32x4){0.f, 0.f, 0.f, 0.f};
    const unsigned short* gs[4];
    int ls[4];
#pragma unroll
    for (int s = 0; s < 4; ++s) {
        int qq = w * 4 + s;
        int row0 = (qq & 7) * 16;
        const unsigned short* base; int lb;
        if (qq < 8)       { base = x1h + ((size_t)b * 512 + n0) * 1024; lb = 0; }
        else if (qq < 16) { base = x1l + ((size_t)b * 512 + n0) * 1024; lb = 4096; }
        else if (qq < 24) { base = x2h + ((size_t)b * 512 + m0) * 1024; lb = 8192; }
        else              { base = x2l + ((size_t)b * 512 + m0) * 1024; lb = 12288; }
        gs[s] = base + (size_t)(row0 + (l >> 2)) * 1024 + (l & 3) * 8;
        ls[s] = lb + row0 * 32 + l * 8;
    }
    // prologue: issue tile 0 (no barrier needed; iter-0 vmcnt(4)+barrier covers)
#pragma unroll
    for (int s = 0; s < 4; ++s)
        ASYNC_COPY16(gs[s], &S[0][ls[s]]);
    int cur = 0;
    for (int kk = 0; kk < 1024; kk += 32) {
        if (kk + 32 < 1024) {
#pragma unroll
            for (int s = 0; s < 4; ++s)
                ASYNC_COPY16(gs[s] + kk + 32, &S[cur ^ 1][ls[s]]);
            __builtin_amdgcn_sched_barrier(0);
            asm volatile("s_waitcnt vmcnt(4)" ::: "memory");   // tile-t landed, t+1 in flight
        } else {
            asm volatile("s_waitcnt vmcnt(0)" ::: "memory");   // final tile
        }
        __builtin_amdgcn_s_barrier();
        __builtin_amdgcn_sched_barrier(0);
        const unsigned short* Sb = S[cur];
        short8 ah[4], al[4], bh[2], bl[2];
#pragma unroll
        for (int i = 0; i < 4; ++i) {
            int off = (wr + i * 16 + lane16) * 32 + q8;
            ah[i] = *(const short8*)&Sb[off];
            al[i] = *(const short8*)&Sb[4096 + off];
        }
#pragma unroll
        for (int j = 0; j < 2; ++j) {
            int off = (wc + j * 16 + lane16) * 32 + q8;
            bh[j] = *(const short8*)&Sb[8192 + off];
            bl[j] = *(const short8*)&Sb[12288 + off];
        }
#pragma unroll
        for (int i = 0; i < 4; ++i)
#pragma unroll
            for (int j = 0; j < 2; ++j) {
                acc[i][j] = __builtin_amdgcn_mfma_f32_16x16x32_bf16(ah[i], bh[j], acc[i][j], 0, 0, 0);
                acc[i][j] = __builtin_amdgcn_mfma_f32_16x16x32_bf16(ah[i], bl[j], acc[i][j], 0, 0, 0);
                acc[i][j] = __builtin_amdgcn_mfma_f32_16x16x32_bf16(al[i], bh[j], acc[i][j], 0, 0, 0);
            }
        __builtin_amdgcn_sched_barrier(0);
        __builtin_amdgcn_s_barrier();   // all waves done reading buf[cur] before overwrite
        cur ^= 1;
    }
    float* ob = alg + ((size_t)b * 512 + n0 + wr) * 512 + m0 + wc;
    int q4 = q * 4;
#pragma unroll
    for (int i = 0; i < 4; ++i)
#pragma unroll
        for (int j = 0; j < 2; ++j)
#pragma unroll
            for (int r = 0; r < 4; ++r)
                ob[(size_t)(i * 16 + q4 + r) * 512 + j * 16 + lane16] = acc[i][j][r];
    int mk2[2];
#pragma unroll
    for (int j = 0; j < 2; ++j) mk2[j] = mask2[b * 512 + m0 + wc + j * 16 + lane16];
    int mk1r[4][4];
#pragma unroll
    for (int i = 0; i < 4; ++i)
#pragma unroll
        for (int r = 0; r < 4; ++r) mk1r[i][r] = mask1[b * 512 + n0 + wr + i * 16 + q4 + r];
#pragma unroll
    for (int j = 0; j < 2; ++j) {
        float cm = -3.0e38f;
#pragma unroll
        for (int i = 0; i < 4; ++i)
#pragma unroll
            for (int r = 0; r < 4; ++r)
                if (mk1r[i][r]) cm = fmaxf(cm, acc[i][j][r]);
        cm = fmaxf(cm, __shfl_xor(cm, 16));
        cm = fmaxf(cm, __shfl_xor(cm, 32));
        float cs = 0.f;
#pragma unroll
        for (int i = 0; i < 4; ++i)
#pragma unroll
            for (int r = 0; r < 4; ++r)
                cs += mk1r[i][r] ? __expf(acc[i][j][r] - cm) : 0.f;
        cs += __shfl_xor(cs, 16);
        cs += __shfl_xor(cs, 32);
        if (q == 0) {
            size_t o = ((size_t)b * 8 + nt * 2 + (w >> 2)) * 512 + m0 + wc + j * 16 + lane16;
            cp_max[o] = cm;
            cp_sum[o] = cs;
        }
    }
    float* rmS = (float*)&S[0][0];
    float* rsS = rmS + 512;
#pragma unroll
    for (int i = 0; i < 4; ++i)
#pragma unroll
        for (int r = 0; r < 4; ++r) {
            float v0 = acc[i][0][r], v1 = acc[i][1][r];
            float rm = fmaxf(mk2[0] ? v0 : -3.0e38f, mk2[1] ? v1 : -3.0e38f);
            rm = fmaxf(rm, __shfl_xor(rm, 1));
            rm = fmaxf(rm, __shfl_xor(rm, 2));
            rm = fmaxf(rm, __shfl_xor(rm, 4));
            rm = fmaxf(rm, __shfl_xor(rm, 8));
            float rs = (mk2[0] ? __expf(v0 - rm) : 0.f) + (mk2[1] ? __expf(v1 - rm) : 0.f);
            rs += __shfl_xor(rs, 1);
            rs += __shfl_xor(rs, 2);
            rs += __shfl_xor(rs, 4);
            rs += __shfl_xor(rs, 8);
            if (lane16 == 0) {
                int row = i * 16 + q4 + r;
                rmS[w * 64 + row] = rm;
                rsS[w * 64 + row] = rs;
            }
        }
    __syncthreads();
    if (t < 128) {
        int grp = t >> 6, rloc = t & 63;
        float M = -3.0e38f;
#pragma unroll
        for (int ww = 0; ww < 4; ++ww) M = fmaxf(M, rmS[(grp * 4 + ww) * 64 + rloc]);
        float Ssum = 0.f;
#pragma unroll
        for (int ww = 0; ww < 4; ++ww)
            Ssum += rsS[(grp * 4 + ww) * 64 + rloc] * __expf(rmS[(grp * 4 + ww) * 64 + rloc] - M);
        size_t o = ((size_t)b * 4 + mt) * 512 + n0 + t;
        rp_max[o] = M;
        rp_sum[o] = Ssum;
    }
}

// ---------------------------------------------------------------------------
// K3': apply softmax with combine_stats FUSED (each block recomputes its
// 64-row/64-col stats from partials into LDS; K2 kernel eliminated).
// ---------------------------------------------------------------------------
__global__ __launch_bounds__(256) void apply_softmax(
    const float* __restrict__ alg, const int* __restrict__ mask1,
    const int* __restrict__ mask2,
    const float* __restrict__ rp_max, const float* __restrict__ rp_sum,
    const float* __restrict__ cp_max, const float* __restrict__ cp_sum,
    unsigned short* __restrict__ attn12, unsigned short* __restrict__ attn21) {
    int bid = blockIdx.x; int b = bid >> 6; int rem = bid & 63;
    int m0 = (rem >> 3) * 64, n0 = (rem & 7) * 64;
    int t = threadIdx.x;
    __shared__ float lds[64 * 65];
    __shared__ float st[4][64];   // rowmax, rowinv, colmax, colinv (block-local)
    if (t < 64) {
        int n = n0 + t;
        float M = -3.0e38f;
#pragma unroll
        for (int tt = 0; tt < 4; ++tt) M = fmaxf(M, rp_max[((size_t)b * 4 + tt) * 512 + n]);
        float Ssum = 0.f;
#pragma unroll
        for (int tt = 0; tt < 4; ++tt) {
            size_t o = ((size_t)b * 4 + tt) * 512 + n;
            Ssum += rp_sum[o] * __expf(rp_max[o] - M);
        }
        st[0][t] = M; st[1][t] = 1.0f / Ssum;
    } else if (t < 128) {
        int m = m0 + (t - 64);
        float M = -3.0e38f;
#pragma unroll
        for (int tt = 0; tt < 8; ++tt) M = fmaxf(M, cp_max[((size_t)b * 8 + tt) * 512 + m]);
        float Ssum = 0.f;
#pragma unroll
        for (int tt = 0; tt < 8; ++tt) {
            size_t o = ((size_t)b * 8 + tt) * 512 + m;
            Ssum += cp_sum[o] * __expf(cp_max[o] - M);
        }
        st[2][t - 64] = M; st[3][t - 64] = 1.0f / Ssum;
    }
    __syncthreads();
    int jj = t & 63; int ii = t >> 6;
    int mk2 = mask2[b * 512 + m0 + jj];
    unsigned short e12[16];
#pragma unroll
    for (int p = 0; p < 16; ++p) {
        int n = ii + p * 4;
        float v = alg[((size_t)b * 512 + n0 + n) * 512 + m0 + jj];
        lds[n * 65 + jj] = v;
        e12[p] = mk2 ? f2bf(__expf(v - st[0][n]) * st[1][n]) : (unsigned short)0;
    }
    __syncthreads();
#pragma unroll
    for (int p = 0; p < 16; ++p) {
        int n = ii + p * 4;
        attn12[((size_t)b * 512 + n0 + n) * 512 + m0 + jj] = e12[p];
    }
    int mk1 = mask1[b * 512 + n0 + jj];
#pragma unroll
    for (int p = 0; p < 16; ++p) {
        int mm = ii + p * 4;
        float v = lds[jj * 65 + mm];
        unsigned short pv = mk1 ? f2bf(__expf(v - st[2][mm]) * st[3][mm]) : (unsigned short)0;
        attn21[((size_t)b * 512 + m0 + mm) * 512 + n0 + jj] = pv;
    }
}

// ---------------------------------------------------------------------------
// K4: merged PV GEMM (both directions in one grid-2048 launch). T4 loop:
// vmcnt(4) leaves {bv(t+1), A-DMA(t+1)} in flight, confirms A(t) landed;
// lgkmcnt(0) before barrier #2 makes the cross-wave SB ds_writes visible.
// ---------------------------------------------------------------------------
__global__ __launch_bounds__(256) void gemm_pv2(
    const unsigned short* __restrict__ attn12, const unsigned short* __restrict__ x2h,
    const unsigned short* __restrict__ attn21, const unsigned short* __restrict__ x1h,
    float* __restrict__ out1, float* __restrict__ out2) {
    __shared__ unsigned short SA[2][4096];       // [128n][32m] bf16
    __shared__ unsigned int   SB[2][32 * 65];    // [32m][130 u16] padded
    int bid0 = blockIdx.x;
    const unsigned short* P; const unsigned short* V; float* out;
    if (bid0 < 1024) { P = attn12; V = x2h; out = out1; }
    else             { P = attn21; V = x1h; out = out2; }
    int bid = bid0 & 1023;
    int nb = (bid & 7) * 128 + (bid >> 3);  // XCD batch-affinity swizzle
    int b = nb >> 5; int rem = nb & 31;
    int n0 = (rem >> 3) * 128, d0 = (rem & 7) * 128;
    int t = threadIdx.x; int w = t >> 6; int l = t & 63;
    int lane16 = l & 15, q = l >> 4, q8 = q * 8;
    int wr = (w >> 1) * 64, wc = (w & 1) * 64;
    f32x4 acc[4][4];
#pragma unroll
    for (int i = 0; i < 4; ++i)
#pragma unroll
        for (int j = 0; j < 4; ++j) acc[i][j] = (f32x4){0.f, 0.f, 0.f, 0.f};
    const unsigned short* gA = P + ((size_t)b * 512 + n0) * 512;
    const unsigned short* gsA[2];
    int ldsa[2];
#pragma unroll
    for (int s = 0; s < 2; ++s) {
        int a = w * 2 + s;
        gsA[s] = gA + (size_t)(a * 16 + (l >> 2)) * 512 + (l & 3) * 8;
        ldsa[s] = a * 512 + l * 8;
    }
    int dch = l & 15;
    int mloc[2]; mloc[0] = w * 4 + q; mloc[1] = mloc[0] + 16;
    const unsigned short* gB0[2];
#pragma unroll
    for (int s = 0; s < 2; ++s)
        gB0[s] = V + (size_t)b * 524288 + (size_t)mloc[s] * 1024 + d0 + dch * 8;
    union U8 { short8 s; unsigned int u[4]; };
    // prologue: tile 0 fully staged, one-time full drain
    U8 bv[2];
#pragma unroll
    for (int s = 0; s < 2; ++s) bv[s].s = *(const short8*)gB0[s];
#pragma unroll
    for (int s = 0; s < 2; ++s)
        ASYNC_COPY16(gsA[s], &SA[0][ldsa[s]]);
#pragma unroll
    for (int s = 0; s < 2; ++s)
#pragma unroll
        for (int c = 0; c < 4; ++c)
            SB[0][mloc[s] * 65 + dch * 4 + c] = bv[s].u[c];
    __syncthreads();
    int cur = 0;
    for (int kk = 0; kk < 512; kk += 32) {
        int more = (kk + 32 < 512);
        if (more) {
#pragma unroll
            for (int s = 0; s < 2; ++s) bv[s].s = *(const short8*)(gB0[s] + (size_t)(kk + 32) * 1024);
            __builtin_amdgcn_sched_barrier(0);   // keep bv-loads older than A-DMA
#pragma unroll
            for (int s = 0; s < 2; ++s)
                ASYNC_COPY16(gsA[s] + kk + 32, &SA[cur ^ 1][ldsa[s]]);
            __builtin_amdgcn_sched_barrier(0);
            asm volatile("s_waitcnt vmcnt(4)" ::: "memory");   // A(t) landed; {bv,A}(t+1) in flight
        } else {
            asm volatile("s_waitcnt vmcnt(0)" ::: "memory");
        }
        __builtin_amdgcn_s_barrier();
        __builtin_amdgcn_sched_barrier(0);
        short8 af[4];
#pragma unroll
        for (int i = 0; i < 4; ++i)
            af[i] = *(const short8*)&SA[cur][(wr + i * 16 + lane16) * 32 + q8];
        const unsigned short* Bs = (const unsigned short*)SB[cur];
        short8 bf[4];
#pragma unroll
        for (int j = 0; j < 4; ++j) {
            int col = wc + j * 16 + lane16;
#pragma unroll
            for (int e = 0; e < 8; ++e)
                bf[j][e] = (short)Bs[(q8 + e) * 130 + col];
        }
#pragma unroll
        for (int i = 0; i < 4; ++i)
#pragma unroll
            for (int j = 0; j < 4; ++j)
                acc[i][j] = __builtin_amdgcn_mfma_f32_16x16x32_bf16(af[i], bf[j], acc[i][j], 0, 0, 0);
        if (more) {   // write next B tile (buf^1 free since iter t-1's barrier)
#pragma unroll
            for (int s = 0; s < 2; ++s)
#pragma unroll
                for (int c = 0; c < 4; ++c)
                    SB[cur ^ 1][mloc[s] * 65 + dch * 4 + c] = bv[s].u[c];
        }
        asm volatile("s_waitcnt lgkmcnt(0)" ::: "memory");   // SB writes visible
        __builtin_amdgcn_sched_barrier(0);
        __builtin_amdgcn_s_barrier();
        cur ^= 1;
    }
    int q4 = q * 4;
#pragma unroll
    for (int i = 0; i < 4; ++i)
#pragma unroll
        for (int j = 0; j < 4; ++j)
#pragma unroll
            for (int r = 0; r < 4; ++r) {
                int rr = n0 + wr + i * 16 + q4 + r;
                int dd = d0 + wc + j * 16 + lane16;
                out[((size_t)b * 512 + rr) * DD + dd] = acc[i][j][r];
            }
}

// ---------------------------------------------------------------------------
// ws layout (224MB): x1h 0 | x2h 32M | x1l 128M | x2l 160M | alg 192M.
// attn12 @128M (reuses x1l), attn21 @160M (reuses x2l). Partial stats in
// d_out scratch (dead before gemm_pv2 writes it). 4 launches total.
// ---------------------------------------------------------------------------
extern "C" void kernel_launch(void* const* d_in, const int* in_sizes, int n_in,
                              void* d_out, int out_size, void* d_ws, size_t ws_size,
                              hipStream_t stream) {
    const float* x1 = (const float*)d_in[0];
    const float* x2 = (const float*)d_in[1];
    const int* mask1 = (const int*)d_in[2];
    const int* mask2 = (const int*)d_in[3];
    char* ws = (char*)d_ws;
    unsigned short* x1h  = (unsigned short*)(ws);
    unsigned short* x2h  = (unsigned short*)(ws + 33554432UL);
    unsigned short* x1l  = (unsigned short*)(ws + 134217728UL);
    unsigned short* x2l  = (unsigned short*)(ws + 167772160UL);
    float* alg           = (float*)(ws + 201326592UL);
    unsigned short* attn12 = (unsigned short*)(ws + 134217728UL);  // reuses x1l
    unsigned short* attn21 = (unsigned short*)(ws + 167772160UL);  // reuses x2l
    float* out1 = (float*)d_out;
    float* out2 = out1 + (size_t)BB * NN * DD;
    float* rp_max = (float*)d_out;            // [32][4][512]
    float* rp_sum = rp_max + 65536;
    float* cp_max = rp_sum + 65536;           // [32][8][512]
    float* cp_sum = cp_max + 131072;

    convert_split<<<8192, 256, 0, stream>>>(x1, x2, x1h, x1l, x2h, x2l);
    gemm_align<<<512, 512, 0, stream>>>(x1h, x1l, x2h, x2l, mask1, mask2, alg,
                                        rp_max, rp_sum, cp_max, cp_sum);
    apply_softmax<<<2048, 256, 0, stream>>>(alg, mask1, mask2,
                                            rp_max, rp_sum, cp_max, cp_sum,
                                            attn12, attn21);
    gemm_pv2<<<2048, 256, 0, stream>>>(attn12, x2h, attn21, x1h, out1, out2);
}